// Round 4
// baseline (306.011 us; speedup 1.0000x reference)
//
#include <hip/hip_runtime.h>
#include <math.h>

#define BB 8
#define PP 1000
#define NN 1000
#define EE 128
#define HH 8
#define DD 16

#define INV_SQRT_E 0.08838834764831845f   // 1/sqrt(128)
#define INV_SQRT_D 0.25f                   // 1/sqrt(16)

typedef short short8_t __attribute__((ext_vector_type(8)));
typedef float f32x4    __attribute__((ext_vector_type(4)));
typedef __bf16 bf16x4  __attribute__((ext_vector_type(4)));

__device__ __forceinline__ float sigmoid_fast(float x) {
    return 1.f / (1.f + __expf(-x));
}
__device__ __forceinline__ float tanh_fast(float x) {
    x = fminf(fmaxf(x, -15.f), 15.f);
    float e = __expf(2.f * x);
    return (e - 1.f) / (e + 1.f);
}

__device__ __forceinline__ f32x4 mfma16(short8_t a, short8_t b, f32x4 c) {
    return __builtin_amdgcn_mfma_f32_16x16x32_bf16(a, b, c, 0, 0, 0);
}

// sum across the 16 lanes of a DPP row (pure VALU butterfly)
__device__ __forceinline__ float sum16(float x) {
    int v;
    v = __builtin_amdgcn_update_dpp(0, __builtin_bit_cast(int, x), 0xB1, 0xF, 0xF, true);
    x += __builtin_bit_cast(float, v);
    v = __builtin_amdgcn_update_dpp(0, __builtin_bit_cast(int, x), 0x4E, 0xF, 0xF, true);
    x += __builtin_bit_cast(float, v);
    v = __builtin_amdgcn_update_dpp(0, __builtin_bit_cast(int, x), 0x141, 0xF, 0xF, true);
    x += __builtin_bit_cast(float, v);
    v = __builtin_amdgcn_update_dpp(0, __builtin_bit_cast(int, x), 0x140, 0xF, 0xF, true);
    x += __builtin_bit_cast(float, v);
    return x;
}

__device__ __forceinline__ unsigned int pack_bf16(float a, float b) {
    __bf16 x = (__bf16)a, y = (__bf16)b;
    unsigned short ux = __builtin_bit_cast(unsigned short, x);
    unsigned short uy = __builtin_bit_cast(unsigned short, y);
    return (unsigned int)ux | ((unsigned int)uy << 16);
}

// ---------------------------------------------------------------------------
// K1: kv projections -> bf16. K stored [bh][n][d]. V stored TRANSPOSED +
// key-permuted: [bh][d][pos] (1024-slot rows; within each 32-key block,
// key r<16 -> slot 2r, r>=16 -> slot 2(r-16)+1, matching packed-pair P).
// ---------------------------------------------------------------------------
__global__ __launch_bounds__(256) void kv_proj_kernel(
    const float* __restrict__ A,
    const float* __restrict__ Wk_s, const float* __restrict__ Wv_s,
    const float* __restrict__ Wk_t, const float* __restrict__ Wv_t,
    __bf16* __restrict__ kb_s, __bf16* __restrict__ vt_s,
    __bf16* __restrict__ kb_t, __bf16* __restrict__ vt_t)
{
    const int wsel = blockIdx.y;
    const float* W = (wsel == 0) ? Wk_s : (wsel == 1) ? Wv_s : (wsel == 2) ? Wk_t : Wv_t;
    __bf16* KO = (wsel == 0) ? kb_s : kb_t;
    __bf16* VO = (wsel == 1) ? vt_s : vt_t;
    const int r0 = blockIdx.x * 64;
    __shared__ float As[64][16];
    __shared__ float Ws[16][128];
    const int tid = threadIdx.x;
    const int rg = tid >> 5;
    const int cg = tid & 31;
    float acc[8][4] = {};

    for (int k0 = 0; k0 < 128; k0 += 16) {
        {
            int row = tid >> 2, seg = tid & 3;
            float4 av = *(const float4*)&A[(size_t)(r0 + row) * 128 + k0 + seg * 4];
            *(float4*)&As[row][seg * 4] = av;
        }
        {
            int kk = tid >> 4, c = (tid & 15) * 8;
            *(float4*)&Ws[kk][c]     = *(const float4*)&W[(size_t)(k0 + kk) * 128 + c];
            *(float4*)&Ws[kk][c + 4] = *(const float4*)&W[(size_t)(k0 + kk) * 128 + c + 4];
        }
        __syncthreads();
        #pragma unroll
        for (int k = 0; k < 16; ++k) {
            float4 w = *(const float4*)&Ws[k][cg * 4];
            #pragma unroll
            for (int r = 0; r < 8; ++r) {
                float a = As[rg * 8 + r][k];
                acc[r][0] = fmaf(a, w.x, acc[r][0]);
                acc[r][1] = fmaf(a, w.y, acc[r][1]);
                acc[r][2] = fmaf(a, w.z, acc[r][2]);
                acc[r][3] = fmaf(a, w.w, acc[r][3]);
            }
        }
        __syncthreads();
    }
    const int c = cg * 4;
    const int h = c >> 4, d = c & 15;
    if ((wsel & 1) == 0) {
        #pragma unroll
        for (int r = 0; r < 8; ++r) {
            int row = r0 + rg * 8 + r;
            int b = row / 1000, n = row % 1000;
            bf16x4 pk = { (__bf16)acc[r][0], (__bf16)acc[r][1],
                          (__bf16)acc[r][2], (__bf16)acc[r][3] };
            *(bf16x4*)&KO[(((size_t)(b * HH + h) * 1000 + n) << 4) + d] = pk;
        }
    } else {
        #pragma unroll
        for (int r = 0; r < 8; ++r) {
            int row = r0 + rg * 8 + r;
            int b = row / 1000, n = row % 1000;
            int rr = n & 31;
            int pos = (n & ~31) + ((rr < 16) ? (rr << 1) : (((rr - 16) << 1) | 1));
            #pragma unroll
            for (int i = 0; i < 4; ++i) {
                VO[((size_t)((b * HH + h) * 16 + d + i) << 10) + pos] = (__bf16)acc[r][i];
            }
        }
    }
}

// ---------------------------------------------------------------------------
// K2: q_shared / q_task (bf16, [bh][p][d]) and gate (fp32) projections.
// ---------------------------------------------------------------------------
__global__ __launch_bounds__(256) void q_proj_kernel(
    const float* __restrict__ eln, const float* __restrict__ attr,
    const float* __restrict__ Wq_s, const float* __restrict__ Wq_t,
    const float* __restrict__ Wg, const float* __restrict__ bg,
    __bf16* __restrict__ qb_s, __bf16* __restrict__ qb_t, float* __restrict__ gate)
{
    const int wsel = blockIdx.y;
    const float* W = (wsel == 0) ? Wq_s : (wsel == 1) ? Wq_t : Wg;
    const int r0 = blockIdx.x * 64;
    __shared__ float As[64][16];
    __shared__ float Ws[16][128];
    const int tid = threadIdx.x;
    const int rg = tid >> 5;
    const int cg = tid & 31;
    float acc[8][4] = {};

    for (int k0 = 0; k0 < 144; k0 += 16) {
        {
            int row = tid >> 2, seg = tid & 3;
            int k = k0 + seg * 4;
            float4 av = make_float4(0.f, 0.f, 0.f, 0.f);
            if (k + 3 < 128)      av = *(const float4*)&eln[(size_t)(r0 + row) * 128 + k];
            else if (k == 128)    av = *(const float4*)&attr[(size_t)(r0 + row) * 4];
            *(float4*)&As[row][seg * 4] = av;
        }
        {
            int kk = tid >> 4, c = (tid & 15) * 8;
            int k = k0 + kk;
            float4 w0 = make_float4(0.f, 0.f, 0.f, 0.f), w1 = w0;
            if (k < 132) {
                w0 = *(const float4*)&W[(size_t)k * 128 + c];
                w1 = *(const float4*)&W[(size_t)k * 128 + c + 4];
            }
            *(float4*)&Ws[kk][c]     = w0;
            *(float4*)&Ws[kk][c + 4] = w1;
        }
        __syncthreads();
        #pragma unroll
        for (int k = 0; k < 16; ++k) {
            float4 w = *(const float4*)&Ws[k][cg * 4];
            #pragma unroll
            for (int r = 0; r < 8; ++r) {
                float a = As[rg * 8 + r][k];
                acc[r][0] = fmaf(a, w.x, acc[r][0]);
                acc[r][1] = fmaf(a, w.y, acc[r][1]);
                acc[r][2] = fmaf(a, w.z, acc[r][2]);
                acc[r][3] = fmaf(a, w.w, acc[r][3]);
            }
        }
        __syncthreads();
    }
    const int c = cg * 4;
    if (wsel < 2) {
        __bf16* Qo = (wsel == 0) ? qb_s : qb_t;
        const int h = c >> 4, d = c & 15;
        #pragma unroll
        for (int r = 0; r < 8; ++r) {
            int row = r0 + rg * 8 + r;
            int b = row / 1000, p = row % 1000;
            bf16x4 pk = { (__bf16)acc[r][0], (__bf16)acc[r][1],
                          (__bf16)acc[r][2], (__bf16)acc[r][3] };
            *(bf16x4*)&Qo[(((size_t)(b * HH + h) * 1000 + p) << 4) + d] = pk;
        }
    } else {
        float4 bgv = *(const float4*)&bg[c];
        #pragma unroll
        for (int r = 0; r < 8; ++r) {
            int row = r0 + rg * 8 + r;
            float4 g;
            g.x = sigmoid_fast(acc[r][0] + bgv.x);
            g.y = sigmoid_fast(acc[r][1] + bgv.y);
            g.z = sigmoid_fast(acc[r][2] + bgv.z);
            g.w = sigmoid_fast(acc[r][3] + bgv.w);
            *(float4*)&gate[(size_t)row * 128 + c] = g;
        }
    }
}

// ---------------------------------------------------------------------------
// K3: MFMA flash attention, 1 q-tile (16 queries) per wave for max occupancy.
// No online rescaling (scores small). l via MFMA vs ones-fragment.
// ---------------------------------------------------------------------------
__global__ __launch_bounds__(256) void attn_mfma_kernel(
    const __bf16* __restrict__ qb_s, const __bf16* __restrict__ qb_t,
    const __bf16* __restrict__ kb_s, const __bf16* __restrict__ kb_t,
    const __bf16* __restrict__ vt_s, const __bf16* __restrict__ vt_t,
    const float* __restrict__ mask,
    float* __restrict__ att_s, float* __restrict__ att_t)
{
    const int b    = blockIdx.z;
    const int wave = threadIdx.x >> 6;
    const int combo = blockIdx.y * 4 + wave;
    const int br = combo & 1;
    const int h  = combo >> 1;
    const __bf16* Q  = br ? qb_t : qb_s;
    const __bf16* K  = br ? kb_t : kb_s;
    const __bf16* Vt = br ? vt_t : vt_s;
    float* O         = br ? att_t : att_s;
    const int lane = threadIdx.x & 63;
    const int quad = lane >> 4, lq = lane & 15;
    const int bh = b * HH + h;
    const int p0 = blockIdx.x * 16;

    __shared__ unsigned int Plds[4][16][20];   // per-wave 16 rows x 16 uints, +4 pad

    short8_t qA = {};
    if (quad < 2) {
        int p = p0 + lq; if (p > 999) p = 999;
        qA = *(const short8_t*)&Q[(((size_t)bh * 1000 + p) << 4) + quad * 8];
    }
    short8_t onesB = { (short)0x3F80, (short)0x3F80, (short)0x3F80, (short)0x3F80,
                       (short)0x3F80, (short)0x3F80, (short)0x3F80, (short)0x3F80 };

    f32x4 o = {0.f, 0.f, 0.f, 0.f};
    f32x4 l = {0.f, 0.f, 0.f, 0.f};

    const float* mp[4];
    #pragma unroll
    for (int r = 0; r < 4; ++r) {
        int p = p0 + quad * 4 + r; if (p > 999) p = 999;
        mp[r] = mask + ((size_t)b * 1000 + p) * 1000 + lq;
    }

    for (int n0 = 0; n0 < NN; n0 += 32) {
        const bool tail = (n0 + 32 > NN);   // only n0 == 992
        short8_t kB0 = {}, kB1 = {};
        if (quad < 2) {
            int n_0 = n0 + lq, n_1 = n0 + 16 + lq;
            if (tail) { n_0 = min(n_0, 999); n_1 = min(n_1, 999); }
            kB0 = *(const short8_t*)&K[(((size_t)bh * 1000 + n_0) << 4) + quad * 8];
            kB1 = *(const short8_t*)&K[(((size_t)bh * 1000 + n_1) << 4) + quad * 8];
        }
        short8_t vB = *(const short8_t*)&Vt[(((size_t)bh * 16 + lq) << 10) + n0 + quad * 8];

        f32x4 zero = {0.f, 0.f, 0.f, 0.f};
        f32x4 s0 = mfma16(qA, kB0, zero);
        f32x4 s1 = mfma16(qA, kB1, zero);
        float e0[4], e1[4];
        if (!tail) {
            #pragma unroll
            for (int r = 0; r < 4; ++r) {
                e0[r] = __expf(fmaf(s0[r], INV_SQRT_D, mp[r][0]));
                e1[r] = __expf(fmaf(s1[r], INV_SQRT_D, mp[r][16]));
            }
        } else {
            #pragma unroll
            for (int r = 0; r < 4; ++r) {
                float mk = (lq < 8) ? mp[r][0] : 0.f;     // predicated: no OOB
                e0[r] = (lq < 8) ? __expf(fmaf(s0[r], INV_SQRT_D, mk)) : 0.f;
                e1[r] = 0.f;
            }
        }
        __threadfence_block();   // order prior LDS reads before overwrite
        #pragma unroll
        for (int r = 0; r < 4; ++r)
            Plds[wave][quad * 4 + r][lq] = pack_bf16(e0[r], e1[r]);
        __threadfence_block();   // writes before read-back
        uint4 u4 = *(const uint4*)&Plds[wave][lq][quad * 4];
        short8_t aP = __builtin_bit_cast(short8_t, u4);
        o = mfma16(aP, vB, o);
        l = mfma16(aP, onesB, l);

        #pragma unroll
        for (int r = 0; r < 4; ++r) mp[r] += 32;
    }

    #pragma unroll
    for (int r = 0; r < 4; ++r) {
        int p = p0 + quad * 4 + r;
        if (p < 1000)
            O[((size_t)b * 1000 + p) * 128 + h * 16 + lq] = o[r] / l[r];
    }
}

// ---------------------------------------------------------------------------
// K4: combine -> gated in BF16 (consumed by MFMA pointer kernel)
// ---------------------------------------------------------------------------
__global__ __launch_bounds__(256) void combine_kernel(
    const float* __restrict__ att_s, const float* __restrict__ att_t,
    const float* __restrict__ Wc_s, const float* __restrict__ bc_s,
    const float* __restrict__ Wc_t, const float* __restrict__ bc_t,
    const float* __restrict__ gate, __bf16* __restrict__ gatedb)
{
    const int r0 = blockIdx.x * 32;
    __shared__ float As[32][16], At[32][16];
    __shared__ float Ws[16][128], Wt[16][128];
    const int tid = threadIdx.x;
    const int rg = tid >> 5;
    const int cg = tid & 31;
    float accs[4][4] = {}, acct[4][4] = {};

    for (int k0 = 0; k0 < 128; k0 += 16) {
        {
            int t2 = tid & 127, row = t2 >> 2, seg = t2 & 3;
            const float* src = (tid < 128) ? att_s : att_t;
            float* dst = (tid < 128) ? &As[row][seg * 4] : &At[row][seg * 4];
            *(float4*)dst = *(const float4*)&src[(size_t)(r0 + row) * 128 + k0 + seg * 4];
        }
        {
            int kk = tid >> 4, c = (tid & 15) * 8;
            *(float4*)&Ws[kk][c]     = *(const float4*)&Wc_s[(size_t)(k0 + kk) * 128 + c];
            *(float4*)&Ws[kk][c + 4] = *(const float4*)&Wc_s[(size_t)(k0 + kk) * 128 + c + 4];
            *(float4*)&Wt[kk][c]     = *(const float4*)&Wc_t[(size_t)(k0 + kk) * 128 + c];
            *(float4*)&Wt[kk][c + 4] = *(const float4*)&Wc_t[(size_t)(k0 + kk) * 128 + c + 4];
        }
        __syncthreads();
        #pragma unroll
        for (int k = 0; k < 16; ++k) {
            float4 w1 = *(const float4*)&Ws[k][cg * 4];
            float4 w2 = *(const float4*)&Wt[k][cg * 4];
            #pragma unroll
            for (int r = 0; r < 4; ++r) {
                float a1 = As[rg * 4 + r][k];
                float a2 = At[rg * 4 + r][k];
                accs[r][0] = fmaf(a1, w1.x, accs[r][0]);
                accs[r][1] = fmaf(a1, w1.y, accs[r][1]);
                accs[r][2] = fmaf(a1, w1.z, accs[r][2]);
                accs[r][3] = fmaf(a1, w1.w, accs[r][3]);
                acct[r][0] = fmaf(a2, w2.x, acct[r][0]);
                acct[r][1] = fmaf(a2, w2.y, acct[r][1]);
                acct[r][2] = fmaf(a2, w2.z, acct[r][2]);
                acct[r][3] = fmaf(a2, w2.w, acct[r][3]);
            }
        }
        __syncthreads();
    }
    const int c = cg * 4;
    float4 b1 = *(const float4*)&bc_s[c];
    float4 b2 = *(const float4*)&bc_t[c];
    #pragma unroll
    for (int r = 0; r < 4; ++r) {
        int row = r0 + rg * 4 + r;
        float4 g = *(const float4*)&gate[(size_t)row * 128 + c];
        float ox = g.x * (accs[r][0] + b1.x) + (1.f - g.x) * (acct[r][0] + b2.x);
        float oy = g.y * (accs[r][1] + b1.y) + (1.f - g.y) * (acct[r][1] + b2.y);
        float oz = g.z * (accs[r][2] + b1.z) + (1.f - g.z) * (acct[r][2] + b2.z);
        float ow = g.w * (accs[r][3] + b1.w) + (1.f - g.w) * (acct[r][3] + b2.w);
        bf16x4 pk = { (__bf16)ox, (__bf16)oy, (__bf16)oz, (__bf16)ow };
        *(bf16x4*)&gatedb[(size_t)row * 128 + c] = pk;
    }
}

// ---------------------------------------------------------------------------
// K4b: nodes fp32 -> bf16 (row-major [b][n][128])
// ---------------------------------------------------------------------------
__global__ __launch_bounds__(256) void to_bf16_kernel(
    const float* __restrict__ in, __bf16* __restrict__ outb)
{
    int i = (blockIdx.x * 256 + threadIdx.x) * 4;
    float4 v = *(const float4*)&in[i];
    bf16x4 pk = { (__bf16)v.x, (__bf16)v.y, (__bf16)v.z, (__bf16)v.w };
    *(bf16x4*)&outb[i] = pk;
}

// ---------------------------------------------------------------------------
// K5: FUSED pointer scores + clip + mask + row softmax -> probs in d_out.
// Block = 16 q-rows x full N=1000. Wave w owns n-tiles {w, w+4, ...} (16 of
// 64 tiles); e-values stay in registers (no score materialization). exp
// without max-subtraction is safe: 10*tanh in [-10,10]. Row sums: per-lane
// accumulate -> DPP 16-lane butterfly -> tiny LDS cross-wave exchange.
// ---------------------------------------------------------------------------
__global__ __launch_bounds__(256) void pointer_softmax_kernel(
    const __bf16* __restrict__ gb, const __bf16* __restrict__ nb,
    const float* __restrict__ mask, float* __restrict__ out)
{
    const int b    = blockIdx.y;
    const int p0   = blockIdx.x * 16;
    const int wave = threadIdx.x >> 6;
    const int lane = threadIdx.x & 63;
    const int quad = lane >> 4, lq = lane & 15;

    __shared__ float Spart[4][16];

    // A fragments: gated rows p0..p0+15 (m=lq), 4 K-chunks
    short8_t aF[4];
    {
        int pp = p0 + lq; if (pp > 999) pp = 999;
        const __bf16* arow = gb + (((size_t)b * 1000 + pp) << 7) + quad * 8;
        #pragma unroll
        for (int kc = 0; kc < 4; ++kc) aF[kc] = *(const short8_t*)&arow[kc * 32];
    }

    float ev[16][4];
    float psum[4] = {0.f, 0.f, 0.f, 0.f};

    #pragma unroll 4
    for (int i = 0; i < 16; ++i) {
        const int nt = i * 4 + wave;          // 0..63
        const int nn = nt * 16 + lq;
        const bool nv = nn < 1000;
        int nc = nv ? nn : 999;
        const __bf16* brow = nb + (((size_t)b * 1000 + nc) << 7) + quad * 8;
        f32x4 acc = {0.f, 0.f, 0.f, 0.f};
        #pragma unroll
        for (int kc = 0; kc < 4; ++kc) {
            short8_t bF = *(const short8_t*)&brow[kc * 32];
            acc = mfma16(aF[kc], bF, acc);
        }
        #pragma unroll
        for (int r = 0; r < 4; ++r) {
            int p = p0 + quad * 4 + r;
            bool v = nv && (p < 1000);
            size_t midx = v ? ((size_t)b * 1000 + p) * 1000 + nn : 0;
            float mk = mask[midx];
            float sc = 10.f * tanh_fast(acc[r] * INV_SQRT_E);
            float ee = v ? __expf(sc + mk) : 0.f;
            ev[i][r] = ee;
            psum[r] += ee;
        }
    }

    // 16-lane butterfly: full row-sum over this wave's tiles
    #pragma unroll
    for (int r = 0; r < 4; ++r) psum[r] = sum16(psum[r]);
    if (lq == 0) {
        #pragma unroll
        for (int r = 0; r < 4; ++r) Spart[wave][quad * 4 + r] = psum[r];
    }
    __syncthreads();
    float inv[4];
    #pragma unroll
    for (int r = 0; r < 4; ++r) {
        int row = quad * 4 + r;
        float s = Spart[0][row] + Spart[1][row] + Spart[2][row] + Spart[3][row];
        inv[r] = 1.f / s;
    }

    #pragma unroll 4
    for (int i = 0; i < 16; ++i) {
        const int nt = i * 4 + wave;
        const int nn = nt * 16 + lq;
        if (nn < 1000) {
            #pragma unroll
            for (int r = 0; r < 4; ++r) {
                int p = p0 + quad * 4 + r;
                if (p < 1000)
                    out[((size_t)b * 1000 + p) * 1000 + nn] = ev[i][r] * inv[r];
            }
        }
    }
}

// ---------------------------------------------------------------------------
extern "C" void kernel_launch(void* const* d_in, const int* in_sizes, int n_in,
                              void* d_out, int out_size, void* d_ws, size_t ws_size,
                              hipStream_t stream)
{
    const float* eln   = (const float*)d_in[0];
    const float* attr  = (const float*)d_in[1];
    const float* nodes = (const float*)d_in[2];
    const float* mask  = (const float*)d_in[3];
    const float* Wq_s  = (const float*)d_in[4];
    const float* Wk_s  = (const float*)d_in[5];
    const float* Wv_s  = (const float*)d_in[6];
    const float* Wq_t  = (const float*)d_in[7];
    const float* Wk_t  = (const float*)d_in[8];
    const float* Wv_t  = (const float*)d_in[9];
    const float* Wc_s  = (const float*)d_in[10];
    const float* bc_s  = (const float*)d_in[11];
    const float* Wc_t  = (const float*)d_in[12];
    const float* bc_t  = (const float*)d_in[13];
    const float* Wg    = (const float*)d_in[14];
    const float* bg    = (const float*)d_in[15];
    float* out = (float*)d_out;

    char* w = (char*)d_ws;
    const size_t KB_SZ = (size_t)64 * 1000 * 16 * 2;   // 2,048,000 B
    const size_t VT_SZ = (size_t)64 * 16 * 1024 * 2;   // 2,097,152 B
    const size_t F_SZ  = (size_t)8000 * 128 * 4;       // 4,096,000 B
    const size_t H_SZ  = (size_t)8000 * 128 * 2;       // 2,048,000 B
    __bf16* kb_s = (__bf16*)w;            w += KB_SZ;
    __bf16* kb_t = (__bf16*)w;            w += KB_SZ;
    __bf16* qb_s = (__bf16*)w;            w += KB_SZ;
    __bf16* qb_t = (__bf16*)w;            w += KB_SZ;
    __bf16* vt_s = (__bf16*)w;            w += VT_SZ;
    __bf16* vt_t = (__bf16*)w;            w += VT_SZ;
    float* gate  = (float*)w;             w += F_SZ;
    float* att_s = (float*)w;             w += F_SZ;
    float* att_t = (float*)w;             w += F_SZ;
    __bf16* gatedb = (__bf16*)w;          w += H_SZ;
    __bf16* nodesb = (__bf16*)w;          w += H_SZ;

    // zero V-transposed pads so tail B-frags are exact zeros
    hipMemsetAsync(vt_s, 0, 2 * VT_SZ, stream);

    kv_proj_kernel<<<dim3(125, 4), 256, 0, stream>>>(
        nodes, Wk_s, Wv_s, Wk_t, Wv_t, kb_s, vt_s, kb_t, vt_t);
    to_bf16_kernel<<<dim3(1000), 256, 0, stream>>>(nodes, nodesb);
    q_proj_kernel<<<dim3(125, 3), 256, 0, stream>>>(
        eln, attr, Wq_s, Wq_t, Wg, bg, qb_s, qb_t, gate);
    attn_mfma_kernel<<<dim3(63, 4, 8), 256, 0, stream>>>(
        qb_s, qb_t, kb_s, kb_t, vt_s, vt_t, mask, att_s, att_t);
    combine_kernel<<<dim3(250), 256, 0, stream>>>(
        att_s, att_t, Wc_s, bc_s, Wc_t, bc_t, gate, gatedb);
    pointer_softmax_kernel<<<dim3(63, 8), 256, 0, stream>>>(
        gatedb, nodesb, mask, out);
}

// Round 5
// 269.956 us; speedup vs baseline: 1.1336x; 1.1336x over previous
//
#include <hip/hip_runtime.h>
#include <math.h>

#define BB 8
#define PP 1000
#define NN 1000
#define EE 128
#define HH 8
#define DD 16

#define INV_SQRT_E 0.08838834764831845f   // 1/sqrt(128)
#define INV_SQRT_D 0.25f                   // 1/sqrt(16)

typedef short short8_t __attribute__((ext_vector_type(8)));
typedef float f32x4    __attribute__((ext_vector_type(4)));
typedef __bf16 bf16x4  __attribute__((ext_vector_type(4)));
typedef __bf16 bf16x8  __attribute__((ext_vector_type(8)));

__device__ __forceinline__ float sigmoid_fast(float x) {
    return 1.f / (1.f + __expf(-x));
}
__device__ __forceinline__ float tanh_fast(float x) {
    x = fminf(fmaxf(x, -15.f), 15.f);
    float e = __expf(2.f * x);
    return (e - 1.f) / (e + 1.f);
}

__device__ __forceinline__ f32x4 mfma16(short8_t a, short8_t b, f32x4 c) {
    return __builtin_amdgcn_mfma_f32_16x16x32_bf16(a, b, c, 0, 0, 0);
}

// sum across the 16 lanes of a DPP row (pure VALU butterfly)
__device__ __forceinline__ float sum16(float x) {
    int v;
    v = __builtin_amdgcn_update_dpp(0, __builtin_bit_cast(int, x), 0xB1, 0xF, 0xF, true);
    x += __builtin_bit_cast(float, v);
    v = __builtin_amdgcn_update_dpp(0, __builtin_bit_cast(int, x), 0x4E, 0xF, 0xF, true);
    x += __builtin_bit_cast(float, v);
    v = __builtin_amdgcn_update_dpp(0, __builtin_bit_cast(int, x), 0x141, 0xF, 0xF, true);
    x += __builtin_bit_cast(float, v);
    v = __builtin_amdgcn_update_dpp(0, __builtin_bit_cast(int, x), 0x140, 0xF, 0xF, true);
    x += __builtin_bit_cast(float, v);
    return x;
}

__device__ __forceinline__ unsigned int pack_bf16(float a, float b) {
    __bf16 x = (__bf16)a, y = (__bf16)b;
    unsigned short ux = __builtin_bit_cast(unsigned short, x);
    unsigned short uy = __builtin_bit_cast(unsigned short, y);
    return (unsigned int)ux | ((unsigned int)uy << 16);
}

// ---------------------------------------------------------------------------
// K0a: weights -> transposed bf16 Wtb. layout Wt[n][k] (k padded), offsets:
//  0:k_s 16384:v_s 32768:k_t 49152:v_t | 65536:q_s 86016:q_t 106496:g (K=160)
//  126976:c_s 143360:c_t
// ---------------------------------------------------------------------------
__global__ void conv_w_kernel(
    const float* __restrict__ Wk_s, const float* __restrict__ Wv_s,
    const float* __restrict__ Wk_t, const float* __restrict__ Wv_t,
    const float* __restrict__ Wq_s, const float* __restrict__ Wq_t,
    const float* __restrict__ Wg,   const float* __restrict__ Wc_s,
    const float* __restrict__ Wc_t, __bf16* __restrict__ Wtb)
{
    const int m = blockIdx.x;
    const float* srcs[9] = {Wk_s, Wv_s, Wk_t, Wv_t, Wq_s, Wq_t, Wg, Wc_s, Wc_t};
    const int   srcKs[9] = {128, 128, 128, 128, 132, 132, 132, 128, 128};
    const int   kpads[9] = {128, 128, 128, 128, 160, 160, 160, 128, 128};
    const size_t offs[9] = {0, 16384, 32768, 49152, 65536, 86016, 106496, 126976, 143360};
    const float* src = srcs[m];
    const int sK = srcKs[m], kp = kpads[m];
    const size_t off = offs[m];
    for (int idx = threadIdx.x; idx < 128 * kp; idx += 256) {
        int n = idx / kp, k = idx - n * kp;
        Wtb[off + idx] = (__bf16)((k < sK) ? src[(size_t)k * 128 + n] : 0.f);
    }
}

// ---------------------------------------------------------------------------
// K0b: nodes fp32 -> bf16 [8000][128]
// ---------------------------------------------------------------------------
__global__ __launch_bounds__(256) void to_bf16_kernel(
    const float* __restrict__ in, __bf16* __restrict__ outb)
{
    int i = (blockIdx.x * 256 + threadIdx.x) * 4;
    float4 v = *(const float4*)&in[i];
    bf16x4 pk = { (__bf16)v.x, (__bf16)v.y, (__bf16)v.z, (__bf16)v.w };
    *(bf16x4*)&outb[i] = pk;
}

// ---------------------------------------------------------------------------
// K0c: inb[8000][160] = concat(eln[128], attr[4], zeros[28]) in bf16
// 160000 8-col segments; grid 625 x 256.
// ---------------------------------------------------------------------------
__global__ __launch_bounds__(256) void concat_inb_kernel(
    const float* __restrict__ eln, const float* __restrict__ attr,
    __bf16* __restrict__ inb)
{
    int t = blockIdx.x * 256 + threadIdx.x;
    int row = t / 20, seg = t - row * 20;
    bf16x8 o = {};
    if (seg < 16) {
        const float* p = &eln[(size_t)row * 128 + seg * 8];
        float4 a = *(const float4*)p, b = *(const float4*)(p + 4);
        o = bf16x8{ (__bf16)a.x, (__bf16)a.y, (__bf16)a.z, (__bf16)a.w,
                    (__bf16)b.x, (__bf16)b.y, (__bf16)b.z, (__bf16)b.w };
    } else if (seg == 16) {
        float4 a = *(const float4*)&attr[(size_t)row * 4];
        o = bf16x8{ (__bf16)a.x, (__bf16)a.y, (__bf16)a.z, (__bf16)a.w,
                    (__bf16)0.f, (__bf16)0.f, (__bf16)0.f, (__bf16)0.f };
    }
    *(bf16x8*)&inb[(size_t)row * 160 + seg * 8] = o;
}

// ---------------------------------------------------------------------------
// K1: MFMA projections. Wave = 16 rows x 128 cols. blockIdx.y = wsel:
// 0..3 kv (A=nodesb,K=128), 4..5 q (A=inb,K=160), 6 gate (A=inb,K=160).
// B-frags straight from global Wt[n][k] (L1-resident, 32-40 KB).
// ---------------------------------------------------------------------------
template<int NC>
__device__ __forceinline__ void proj_body(
    const __bf16* __restrict__ A, const __bf16* __restrict__ W,
    f32x4 acc[8], int r0, int quad, int lq)
{
    const int K = NC * 32;
    short8_t aF[NC];
    #pragma unroll
    for (int c = 0; c < NC; ++c)
        aF[c] = *(const short8_t*)&A[(size_t)(r0 + lq) * K + c * 32 + quad * 8];
    #pragma unroll
    for (int nt = 0; nt < 8; ++nt) {
        acc[nt] = f32x4{0.f, 0.f, 0.f, 0.f};
        #pragma unroll
        for (int c = 0; c < NC; ++c) {
            short8_t bF = *(const short8_t*)&W[(size_t)(nt * 16 + lq) * K + c * 32 + quad * 8];
            acc[nt] = mfma16(aF[c], bF, acc[nt]);
        }
    }
}

__global__ __launch_bounds__(256) void proj_mfma_kernel(
    const __bf16* __restrict__ nodesb, const __bf16* __restrict__ inb,
    const __bf16* __restrict__ Wtb, const float* __restrict__ bg,
    __bf16* __restrict__ kb_s, __bf16* __restrict__ vt_s,
    __bf16* __restrict__ kb_t, __bf16* __restrict__ vt_t,
    __bf16* __restrict__ qb_s, __bf16* __restrict__ qb_t,
    float* __restrict__ gate)
{
    const int wsel = blockIdx.y;
    const int wave = threadIdx.x >> 6, lane = threadIdx.x & 63;
    const int quad = lane >> 4, lq = lane & 15;
    const int r0 = blockIdx.x * 64 + wave * 16;

    f32x4 acc[8];
    if (wsel < 4) {
        proj_body<4>(nodesb, Wtb + (size_t)wsel * 16384, acc, r0, quad, lq);
    } else {
        proj_body<5>(inb, Wtb + 65536 + (size_t)(wsel - 4) * 20480, acc, r0, quad, lq);
    }

    if (wsel == 0 || wsel == 2 || wsel == 4 || wsel == 5) {
        // K or Q: [bh][idx][d], h = nt, d = lq
        __bf16* O = (wsel == 0) ? kb_s : (wsel == 2) ? kb_t : (wsel == 4) ? qb_s : qb_t;
        #pragma unroll
        for (int r = 0; r < 4; ++r) {
            int m = r0 + quad * 4 + r;
            int b = m / 1000, n = m - b * 1000;
            #pragma unroll
            for (int nt = 0; nt < 8; ++nt)
                O[(((size_t)(b * 8 + nt) * 1000 + n) << 4) + lq] = (__bf16)acc[nt][r];
        }
    } else if (wsel == 1 || wsel == 3) {
        // V transposed+permuted: [bh][d][pos], d = lq
        __bf16* O = (wsel == 1) ? vt_s : vt_t;
        #pragma unroll
        for (int r = 0; r < 4; ++r) {
            int m = r0 + quad * 4 + r;
            int b = m / 1000, n = m - b * 1000;
            int rr = n & 31;
            int pos = (n & ~31) + ((rr < 16) ? (rr << 1) : (((rr - 16) << 1) | 1));
            #pragma unroll
            for (int nt = 0; nt < 8; ++nt)
                O[(((size_t)(b * 8 + nt) * 16 + lq) << 10) + pos] = (__bf16)acc[nt][r];
        }
    } else {
        // gate: sigmoid(acc + bg), fp32 [m][128]
        #pragma unroll
        for (int nt = 0; nt < 8; ++nt) {
            float bias = bg[nt * 16 + lq];
            #pragma unroll
            for (int r = 0; r < 4; ++r) {
                int m = r0 + quad * 4 + r;
                gate[(size_t)m * 128 + nt * 16 + lq] = sigmoid_fast(acc[nt][r] + bias);
            }
        }
    }
}

// ---------------------------------------------------------------------------
// K2: MFMA flash attention (R3 config: 2 q-tiles/wave, grid 32x4x8).
// No online rescaling (scores small). l via MFMA vs ones-fragment.
// ---------------------------------------------------------------------------
__global__ __launch_bounds__(256) void attn_mfma_kernel(
    const __bf16* __restrict__ qb_s, const __bf16* __restrict__ qb_t,
    const __bf16* __restrict__ kb_s, const __bf16* __restrict__ kb_t,
    const __bf16* __restrict__ vt_s, const __bf16* __restrict__ vt_t,
    const float* __restrict__ mask,
    float* __restrict__ att_s, float* __restrict__ att_t)
{
    const int b    = blockIdx.z;
    const int wave = threadIdx.x >> 6;
    const int combo = blockIdx.y * 4 + wave;
    const int br = combo & 1;
    const int h  = combo >> 1;
    const __bf16* Q  = br ? qb_t : qb_s;
    const __bf16* K  = br ? kb_t : kb_s;
    const __bf16* Vt = br ? vt_t : vt_s;
    float* O         = br ? att_t : att_s;
    const int lane = threadIdx.x & 63;
    const int quad = lane >> 4, lq = lane & 15;
    const int bh = b * HH + h;
    const int p0 = blockIdx.x * 32;

    __shared__ unsigned int Plds[4][16][20];   // per-wave 16 rows x 16 uints, +4 pad

    short8_t qA[2] = {};
    if (quad < 2) {
        #pragma unroll
        for (int t = 0; t < 2; ++t) {
            int p = p0 + t * 16 + lq; if (p > 999) p = 999;
            qA[t] = *(const short8_t*)&Q[(((size_t)bh * 1000 + p) << 4) + quad * 8];
        }
    }
    short8_t onesB = { (short)0x3F80, (short)0x3F80, (short)0x3F80, (short)0x3F80,
                       (short)0x3F80, (short)0x3F80, (short)0x3F80, (short)0x3F80 };

    f32x4 o[2] = { {0.f,0.f,0.f,0.f}, {0.f,0.f,0.f,0.f} };
    f32x4 l[2] = { {0.f,0.f,0.f,0.f}, {0.f,0.f,0.f,0.f} };

    const float* mp[2][4];
    #pragma unroll
    for (int t = 0; t < 2; ++t)
        #pragma unroll
        for (int r = 0; r < 4; ++r) {
            int p = p0 + t * 16 + quad * 4 + r; if (p > 999) p = 999;
            mp[t][r] = mask + ((size_t)b * 1000 + p) * 1000 + lq;
        }

    for (int n0 = 0; n0 < NN; n0 += 32) {
        const bool tail = (n0 + 32 > NN);   // only n0 == 992
        short8_t kB0 = {}, kB1 = {};
        if (quad < 2) {
            int n_0 = n0 + lq, n_1 = n0 + 16 + lq;
            if (tail) { n_0 = min(n_0, 999); n_1 = min(n_1, 999); }
            kB0 = *(const short8_t*)&K[(((size_t)bh * 1000 + n_0) << 4) + quad * 8];
            kB1 = *(const short8_t*)&K[(((size_t)bh * 1000 + n_1) << 4) + quad * 8];
        }
        short8_t vB = *(const short8_t*)&Vt[(((size_t)bh * 16 + lq) << 10) + n0 + quad * 8];

        #pragma unroll
        for (int t = 0; t < 2; ++t) {
            f32x4 zero = {0.f, 0.f, 0.f, 0.f};
            f32x4 s0 = mfma16(qA[t], kB0, zero);
            f32x4 s1 = mfma16(qA[t], kB1, zero);
            float e0[4], e1[4];
            if (!tail) {
                #pragma unroll
                for (int r = 0; r < 4; ++r) {
                    e0[r] = __expf(fmaf(s0[r], INV_SQRT_D, mp[t][r][0]));
                    e1[r] = __expf(fmaf(s1[r], INV_SQRT_D, mp[t][r][16]));
                }
            } else {
                #pragma unroll
                for (int r = 0; r < 4; ++r) {
                    float mk = (lq < 8) ? mp[t][r][0] : 0.f;     // predicated: no OOB
                    e0[r] = (lq < 8) ? __expf(fmaf(s0[r], INV_SQRT_D, mk)) : 0.f;
                    e1[r] = 0.f;
                }
            }
            __threadfence_block();   // order prior LDS reads before overwrite
            #pragma unroll
            for (int r = 0; r < 4; ++r)
                Plds[wave][quad * 4 + r][lq] = pack_bf16(e0[r], e1[r]);
            __threadfence_block();   // writes before read-back
            uint4 u4 = *(const uint4*)&Plds[wave][lq][quad * 4];
            short8_t aP = __builtin_bit_cast(short8_t, u4);
            o[t] = mfma16(aP, vB, o[t]);
            l[t] = mfma16(aP, onesB, l[t]);
        }
        #pragma unroll
        for (int t = 0; t < 2; ++t)
            #pragma unroll
            for (int r = 0; r < 4; ++r) mp[t][r] += 32;
    }

    #pragma unroll
    for (int t = 0; t < 2; ++t)
        #pragma unroll
        for (int r = 0; r < 4; ++r) {
            int p = p0 + t * 16 + quad * 4 + r;
            if (p < 1000)
                O[((size_t)b * 1000 + p) * 128 + h * 16 + lq] = o[t][r] / l[t][r];
        }
}

// ---------------------------------------------------------------------------
// K3: MFMA combine: gated = g*(att_s@Wc_s+bc_s) + (1-g)*(att_t@Wc_t+bc_t)
// A = att fp32 -> bf16 frags in-kernel. Wave = 16 rows x 128 cols, both GEMMs.
// ---------------------------------------------------------------------------
__global__ __launch_bounds__(256) void combine_mfma_kernel(
    const float* __restrict__ att_s, const float* __restrict__ att_t,
    const __bf16* __restrict__ Wtb,
    const float* __restrict__ bc_s, const float* __restrict__ bc_t,
    const float* __restrict__ gate, __bf16* __restrict__ gatedb)
{
    const int wave = threadIdx.x >> 6, lane = threadIdx.x & 63;
    const int quad = lane >> 4, lq = lane & 15;
    const int r0 = blockIdx.x * 64 + wave * 16;
    const __bf16* Ws = Wtb + 126976;
    const __bf16* Wt = Wtb + 143360;

    short8_t aS[4], aT[4];
    #pragma unroll
    for (int c = 0; c < 4; ++c) {
        const float* ps = &att_s[(size_t)(r0 + lq) * 128 + c * 32 + quad * 8];
        const float* pt = &att_t[(size_t)(r0 + lq) * 128 + c * 32 + quad * 8];
        float4 x = *(const float4*)ps, y = *(const float4*)(ps + 4);
        bf16x8 s8 = { (__bf16)x.x, (__bf16)x.y, (__bf16)x.z, (__bf16)x.w,
                      (__bf16)y.x, (__bf16)y.y, (__bf16)y.z, (__bf16)y.w };
        aS[c] = __builtin_bit_cast(short8_t, s8);
        x = *(const float4*)pt; y = *(const float4*)(pt + 4);
        bf16x8 t8 = { (__bf16)x.x, (__bf16)x.y, (__bf16)x.z, (__bf16)x.w,
                      (__bf16)y.x, (__bf16)y.y, (__bf16)y.z, (__bf16)y.w };
        aT[c] = __builtin_bit_cast(short8_t, t8);
    }
    f32x4 accS[8], accT[8];
    #pragma unroll
    for (int nt = 0; nt < 8; ++nt) {
        accS[nt] = f32x4{0.f,0.f,0.f,0.f};
        accT[nt] = f32x4{0.f,0.f,0.f,0.f};
        #pragma unroll
        for (int c = 0; c < 4; ++c) {
            short8_t bS = *(const short8_t*)&Ws[(size_t)(nt * 16 + lq) * 128 + c * 32 + quad * 8];
            short8_t bT = *(const short8_t*)&Wt[(size_t)(nt * 16 + lq) * 128 + c * 32 + quad * 8];
            accS[nt] = mfma16(aS[c], bS, accS[nt]);
            accT[nt] = mfma16(aT[c], bT, accT[nt]);
        }
    }
    #pragma unroll
    for (int nt = 0; nt < 8; ++nt) {
        int f = nt * 16 + lq;
        float b1 = bc_s[f], b2 = bc_t[f];
        #pragma unroll
        for (int r = 0; r < 4; ++r) {
            int m = r0 + quad * 4 + r;
            float g = gate[(size_t)m * 128 + f];
            float val = g * (accS[nt][r] + b1) + (1.f - g) * (accT[nt][r] + b2);
            gatedb[(size_t)m * 128 + f] = (__bf16)val;
        }
    }
}

// ---------------------------------------------------------------------------
// K4: FUSED pointer scores + clip + mask + row softmax -> probs in d_out.
// Block = 16 q-rows x full N. FULLY unrolled so ev[16][4] stays in VGPRs.
// ---------------------------------------------------------------------------
__global__ __launch_bounds__(256) void pointer_softmax_kernel(
    const __bf16* __restrict__ gb, const __bf16* __restrict__ nb,
    const float* __restrict__ mask, float* __restrict__ out)
{
    const int b    = blockIdx.y;
    const int p0   = blockIdx.x * 16;
    const int wave = threadIdx.x >> 6;
    const int lane = threadIdx.x & 63;
    const int quad = lane >> 4, lq = lane & 15;

    __shared__ float Spart[4][16];

    short8_t aF[4];
    {
        int pp = p0 + lq; if (pp > 999) pp = 999;
        const __bf16* arow = gb + (((size_t)b * 1000 + pp) << 7) + quad * 8;
        #pragma unroll
        for (int kc = 0; kc < 4; ++kc) aF[kc] = *(const short8_t*)&arow[kc * 32];
    }

    float ev[16][4];
    float psum[4] = {0.f, 0.f, 0.f, 0.f};

    #pragma unroll
    for (int i = 0; i < 16; ++i) {
        const int nt = i * 4 + wave;          // 0..63
        const int nn = nt * 16 + lq;
        const bool nv = nn < 1000;
        int nc = nv ? nn : 999;
        const __bf16* brow = nb + (((size_t)b * 1000 + nc) << 7) + quad * 8;
        f32x4 acc = {0.f, 0.f, 0.f, 0.f};
        #pragma unroll
        for (int kc = 0; kc < 4; ++kc) {
            short8_t bF = *(const short8_t*)&brow[kc * 32];
            acc = mfma16(aF[kc], bF, acc);
        }
        #pragma unroll
        for (int r = 0; r < 4; ++r) {
            int p = p0 + quad * 4 + r;
            bool v = nv && (p < 1000);
            size_t midx = v ? ((size_t)b * 1000 + p) * 1000 + nn : 0;
            float mk = mask[midx];
            float sc = 10.f * tanh_fast(acc[r] * INV_SQRT_E);
            float ee = v ? __expf(sc + mk) : 0.f;
            ev[i][r] = ee;
            psum[r] += ee;
        }
    }

    #pragma unroll
    for (int r = 0; r < 4; ++r) psum[r] = sum16(psum[r]);
    if (lq == 0) {
        #pragma unroll
        for (int r = 0; r < 4; ++r) Spart[wave][quad * 4 + r] = psum[r];
    }
    __syncthreads();
    float inv[4];
    #pragma unroll
    for (int r = 0; r < 4; ++r) {
        int row = quad * 4 + r;
        float s = Spart[0][row] + Spart[1][row] + Spart[2][row] + Spart[3][row];
        inv[r] = 1.f / s;
    }

    #pragma unroll
    for (int i = 0; i < 16; ++i) {
        const int nt = i * 4 + wave;
        const int nn = nt * 16 + lq;
        if (nn < 1000) {
            #pragma unroll
            for (int r = 0; r < 4; ++r) {
                int p = p0 + quad * 4 + r;
                if (p < 1000)
                    out[((size_t)b * 1000 + p) * 1000 + nn] = ev[i][r] * inv[r];
            }
        }
    }
}

// ---------------------------------------------------------------------------
extern "C" void kernel_launch(void* const* d_in, const int* in_sizes, int n_in,
                              void* d_out, int out_size, void* d_ws, size_t ws_size,
                              hipStream_t stream)
{
    const float* eln   = (const float*)d_in[0];
    const float* attr  = (const float*)d_in[1];
    const float* nodes = (const float*)d_in[2];
    const float* mask  = (const float*)d_in[3];
    const float* Wq_s  = (const float*)d_in[4];
    const float* Wk_s  = (const float*)d_in[5];
    const float* Wv_s  = (const float*)d_in[6];
    const float* Wq_t  = (const float*)d_in[7];
    const float* Wk_t  = (const float*)d_in[8];
    const float* Wv_t  = (const float*)d_in[9];
    const float* Wc_s  = (const float*)d_in[10];
    const float* bc_s  = (const float*)d_in[11];
    const float* Wc_t  = (const float*)d_in[12];
    const float* bc_t  = (const float*)d_in[13];
    const float* Wg    = (const float*)d_in[14];
    const float* bg    = (const float*)d_in[15];
    float* out = (float*)d_out;

    char* w = (char*)d_ws;
    const size_t KB_SZ = (size_t)8 * 8 * 1000 * 16 * 2;   // 2,048,000 B
    const size_t VT_SZ = (size_t)8 * 8 * 16 * 1024 * 2;   // 2,097,152 B
    const size_t F_SZ  = (size_t)8000 * 128 * 4;          // 4,096,000 B
    const size_t H_SZ  = (size_t)8000 * 128 * 2;          // 2,048,000 B
    const size_t IN_SZ = (size_t)8000 * 160 * 2;          // 2,560,000 B
    __bf16* kb_s = (__bf16*)w;            w += KB_SZ;
    __bf16* kb_t = (__bf16*)w;            w += KB_SZ;
    __bf16* qb_s = (__bf16*)w;            w += KB_SZ;
    __bf16* qb_t = (__bf16*)w;            w += KB_SZ;
    __bf16* vt_s = (__bf16*)w;            w += VT_SZ;
    __bf16* vt_t = (__bf16*)w;            w += VT_SZ;
    float* gate  = (float*)w;             w += F_SZ;
    float* att_s = (float*)w;             w += F_SZ;
    float* att_t = (float*)w;             w += F_SZ;
    __bf16* gatedb = (__bf16*)w;          w += H_SZ;
    __bf16* nodesb = (__bf16*)w;          w += H_SZ;
    __bf16* inb    = (__bf16*)w;          w += IN_SZ;
    __bf16* Wtb    = (__bf16*)w;          w += 320000;

    // zero V-transposed pads so tail B-frags are exact zeros
    hipMemsetAsync(vt_s, 0, 2 * VT_SZ, stream);

    conv_w_kernel<<<dim3(9), 256, 0, stream>>>(
        Wk_s, Wv_s, Wk_t, Wv_t, Wq_s, Wq_t, Wg, Wc_s, Wc_t, Wtb);
    to_bf16_kernel<<<dim3(1000), 256, 0, stream>>>(nodes, nodesb);
    concat_inb_kernel<<<dim3(625), 256, 0, stream>>>(eln, attr, inb);
    proj_mfma_kernel<<<dim3(125, 7), 256, 0, stream>>>(
        nodesb, inb, Wtb, bg, kb_s, vt_s, kb_t, vt_t, qb_s, qb_t, gate);
    attn_mfma_kernel<<<dim3(32, 4, 8), 256, 0, stream>>>(
        qb_s, qb_t, kb_s, kb_t, vt_s, vt_t, mask, att_s, att_t);
    combine_mfma_kernel<<<dim3(125), 256, 0, stream>>>(
        att_s, att_t, Wtb, bc_s, bc_t, gate, gatedb);
    pointer_softmax_kernel<<<dim3(63, 8), 256, 0, stream>>>(
        gatedb, nodesb, mask, out);
}

// Round 6
// 249.987 us; speedup vs baseline: 1.2241x; 1.0799x over previous
//
#include <hip/hip_runtime.h>
#include <math.h>

#define BB 8
#define PP 1000
#define NN 1000
#define EE 128
#define HH 8
#define DD 16

#define INV_SQRT_E 0.08838834764831845f   // 1/sqrt(128)
#define INV_SQRT_D 0.25f                   // 1/sqrt(16)

typedef short short8_t __attribute__((ext_vector_type(8)));
typedef float f32x4    __attribute__((ext_vector_type(4)));
typedef __bf16 bf16x4  __attribute__((ext_vector_type(4)));
typedef __bf16 bf16x8  __attribute__((ext_vector_type(8)));

__device__ __forceinline__ float sigmoid_fast(float x) {
    return 1.f / (1.f + __expf(-x));
}
__device__ __forceinline__ float tanh_fast(float x) {
    x = fminf(fmaxf(x, -15.f), 15.f);
    float e = __expf(2.f * x);
    return (e - 1.f) / (e + 1.f);
}

__device__ __forceinline__ f32x4 mfma16(short8_t a, short8_t b, f32x4 c) {
    return __builtin_amdgcn_mfma_f32_16x16x32_bf16(a, b, c, 0, 0, 0);
}

// sum across the 16 lanes of a DPP row (pure VALU butterfly)
__device__ __forceinline__ float sum16(float x) {
    int v;
    v = __builtin_amdgcn_update_dpp(0, __builtin_bit_cast(int, x), 0xB1, 0xF, 0xF, true);
    x += __builtin_bit_cast(float, v);
    v = __builtin_amdgcn_update_dpp(0, __builtin_bit_cast(int, x), 0x4E, 0xF, 0xF, true);
    x += __builtin_bit_cast(float, v);
    v = __builtin_amdgcn_update_dpp(0, __builtin_bit_cast(int, x), 0x141, 0xF, 0xF, true);
    x += __builtin_bit_cast(float, v);
    v = __builtin_amdgcn_update_dpp(0, __builtin_bit_cast(int, x), 0x140, 0xF, 0xF, true);
    x += __builtin_bit_cast(float, v);
    return x;
}

__device__ __forceinline__ unsigned int pack_bf16(float a, float b) {
    __bf16 x = (__bf16)a, y = (__bf16)b;
    unsigned short ux = __builtin_bit_cast(unsigned short, x);
    unsigned short uy = __builtin_bit_cast(unsigned short, y);
    return (unsigned int)ux | ((unsigned int)uy << 16);
}

// ---------------------------------------------------------------------------
// K0a: weights -> transposed bf16 Wtb via LDS-tiled transpose (coalesced both
// ways). layout Wt[n][k] (k padded), offsets as in proj kernel.
// grid (9 weights, 5 k-tiles of 32)
// ---------------------------------------------------------------------------
__global__ __launch_bounds__(256) void conv_w_kernel(
    const float* __restrict__ Wk_s, const float* __restrict__ Wv_s,
    const float* __restrict__ Wk_t, const float* __restrict__ Wv_t,
    const float* __restrict__ Wq_s, const float* __restrict__ Wq_t,
    const float* __restrict__ Wg,   const float* __restrict__ Wc_s,
    const float* __restrict__ Wc_t, __bf16* __restrict__ Wtb)
{
    const int m = blockIdx.x, kt = blockIdx.y;
    const float* srcs[9] = {Wk_s, Wv_s, Wk_t, Wv_t, Wq_s, Wq_t, Wg, Wc_s, Wc_t};
    const int   srcKs[9] = {128, 128, 128, 128, 132, 132, 132, 128, 128};
    const int   kpads[9] = {128, 128, 128, 128, 160, 160, 160, 128, 128};
    const size_t offs[9] = {0, 16384, 32768, 49152, 65536, 86016, 106496, 126976, 143360};
    const int kp = kpads[m];
    if (kt * 32 >= kp) return;
    const float* src = srcs[m];
    const int sK = srcKs[m];
    const size_t off = offs[m];
    __shared__ float tile[32][129];
    const int tid = threadIdx.x;
    for (int j = tid; j < 32 * 128; j += 256) {
        int kk = j >> 7, n = j & 127;
        int k = kt * 32 + kk;
        tile[kk][n] = (k < sK) ? src[(size_t)k * 128 + n] : 0.f;
    }
    __syncthreads();
    for (int j = tid; j < 32 * 128; j += 256) {
        int n = j >> 5, kk = j & 31;
        Wtb[off + (size_t)n * kp + kt * 32 + kk] = (__bf16)tile[kk][n];
    }
}

// ---------------------------------------------------------------------------
// K0b: nodes fp32 -> bf16 [8000][128]
// ---------------------------------------------------------------------------
__global__ __launch_bounds__(256) void to_bf16_kernel(
    const float* __restrict__ in, __bf16* __restrict__ outb)
{
    int i = (blockIdx.x * 256 + threadIdx.x) * 4;
    float4 v = *(const float4*)&in[i];
    bf16x4 pk = { (__bf16)v.x, (__bf16)v.y, (__bf16)v.z, (__bf16)v.w };
    *(bf16x4*)&outb[i] = pk;
}

// ---------------------------------------------------------------------------
// K0c: inb[8000][160] = concat(eln[128], attr[4], zeros[28]) in bf16
// ---------------------------------------------------------------------------
__global__ __launch_bounds__(256) void concat_inb_kernel(
    const float* __restrict__ eln, const float* __restrict__ attr,
    __bf16* __restrict__ inb)
{
    int t = blockIdx.x * 256 + threadIdx.x;
    int row = t / 20, seg = t - row * 20;
    bf16x8 o = {};
    if (seg < 16) {
        const float* p = &eln[(size_t)row * 128 + seg * 8];
        float4 a = *(const float4*)p, b = *(const float4*)(p + 4);
        o = bf16x8{ (__bf16)a.x, (__bf16)a.y, (__bf16)a.z, (__bf16)a.w,
                    (__bf16)b.x, (__bf16)b.y, (__bf16)b.z, (__bf16)b.w };
    } else if (seg == 16) {
        float4 a = *(const float4*)&attr[(size_t)row * 4];
        o = bf16x8{ (__bf16)a.x, (__bf16)a.y, (__bf16)a.z, (__bf16)a.w,
                    (__bf16)0.f, (__bf16)0.f, (__bf16)0.f, (__bf16)0.f };
    }
    *(bf16x8*)&inb[(size_t)row * 160 + seg * 8] = o;
}

// ---------------------------------------------------------------------------
// K1: MFMA projections. Wave = 16 rows x 128 cols. blockIdx.y = wsel:
// 0..3 kv (A=nodesb,K=128), 4..5 q (A=inb,K=160), 6 gate (A=inb,K=160).
// ---------------------------------------------------------------------------
template<int NC>
__device__ __forceinline__ void proj_body(
    const __bf16* __restrict__ A, const __bf16* __restrict__ W,
    f32x4 acc[8], int r0, int quad, int lq)
{
    const int K = NC * 32;
    short8_t aF[NC];
    #pragma unroll
    for (int c = 0; c < NC; ++c)
        aF[c] = *(const short8_t*)&A[(size_t)(r0 + lq) * K + c * 32 + quad * 8];
    #pragma unroll
    for (int nt = 0; nt < 8; ++nt) {
        acc[nt] = f32x4{0.f, 0.f, 0.f, 0.f};
        #pragma unroll
        for (int c = 0; c < NC; ++c) {
            short8_t bF = *(const short8_t*)&W[(size_t)(nt * 16 + lq) * K + c * 32 + quad * 8];
            acc[nt] = mfma16(aF[c], bF, acc[nt]);
        }
    }
}

__global__ __launch_bounds__(256) void proj_mfma_kernel(
    const __bf16* __restrict__ nodesb, const __bf16* __restrict__ inb,
    const __bf16* __restrict__ Wtb, const float* __restrict__ bg,
    __bf16* __restrict__ kb_s, __bf16* __restrict__ vt_s,
    __bf16* __restrict__ kb_t, __bf16* __restrict__ vt_t,
    __bf16* __restrict__ qb_s, __bf16* __restrict__ qb_t,
    float* __restrict__ gate)
{
    const int wsel = blockIdx.y;
    const int wave = threadIdx.x >> 6, lane = threadIdx.x & 63;
    const int quad = lane >> 4, lq = lane & 15;
    const int r0 = blockIdx.x * 64 + wave * 16;

    f32x4 acc[8];
    if (wsel < 4) {
        proj_body<4>(nodesb, Wtb + (size_t)wsel * 16384, acc, r0, quad, lq);
    } else {
        proj_body<5>(inb, Wtb + 65536 + (size_t)(wsel - 4) * 20480, acc, r0, quad, lq);
    }

    if (wsel == 0 || wsel == 2 || wsel == 4 || wsel == 5) {
        __bf16* O = (wsel == 0) ? kb_s : (wsel == 2) ? kb_t : (wsel == 4) ? qb_s : qb_t;
        #pragma unroll
        for (int r = 0; r < 4; ++r) {
            int m = r0 + quad * 4 + r;
            int b = m / 1000, n = m - b * 1000;
            #pragma unroll
            for (int nt = 0; nt < 8; ++nt)
                O[(((size_t)(b * 8 + nt) * 1000 + n) << 4) + lq] = (__bf16)acc[nt][r];
        }
    } else if (wsel == 1 || wsel == 3) {
        __bf16* O = (wsel == 1) ? vt_s : vt_t;
        #pragma unroll
        for (int r = 0; r < 4; ++r) {
            int m = r0 + quad * 4 + r;
            int b = m / 1000, n = m - b * 1000;
            int rr = n & 31;
            int pos = (n & ~31) + ((rr < 16) ? (rr << 1) : (((rr - 16) << 1) | 1));
            #pragma unroll
            for (int nt = 0; nt < 8; ++nt)
                O[(((size_t)(b * 8 + nt) * 16 + lq) << 10) + pos] = (__bf16)acc[nt][r];
        }
    } else {
        #pragma unroll
        for (int nt = 0; nt < 8; ++nt) {
            float bias = bg[nt * 16 + lq];
            #pragma unroll
            for (int r = 0; r < 4; ++r) {
                int m = r0 + quad * 4 + r;
                gate[(size_t)m * 128 + nt * 16 + lq] = sigmoid_fast(acc[nt][r] + bias);
            }
        }
    }
}

// ---------------------------------------------------------------------------
// K2: MFMA flash attention, SOFTWARE-PIPELINED: K/V/mask for iteration i+1
// prefetched into registers during iteration i; branch-free main loop (31
// iters of 32 keys) + peeled 8-key tail; per-t double LDS P-buffers.
// ---------------------------------------------------------------------------
__global__ __launch_bounds__(256) void attn_mfma_kernel(
    const __bf16* __restrict__ qb_s, const __bf16* __restrict__ qb_t,
    const __bf16* __restrict__ kb_s, const __bf16* __restrict__ kb_t,
    const __bf16* __restrict__ vt_s, const __bf16* __restrict__ vt_t,
    const float* __restrict__ mask,
    float* __restrict__ att_s, float* __restrict__ att_t)
{
    const int b    = blockIdx.z;
    const int wave = threadIdx.x >> 6;
    const int combo = blockIdx.y * 4 + wave;
    const int br = combo & 1;
    const int h  = combo >> 1;
    const __bf16* Q  = br ? qb_t : qb_s;
    const __bf16* K  = br ? kb_t : kb_s;
    const __bf16* Vt = br ? vt_t : vt_s;
    float* O         = br ? att_t : att_s;
    const int lane = threadIdx.x & 63;
    const int quad = lane >> 4, lq = lane & 15;
    const int bh = b * HH + h;
    const int p0 = blockIdx.x * 32;

    __shared__ unsigned int Plds[4][2][16][20];   // [wave][t][row][16+pad]

    short8_t qA[2] = {};
    if (quad < 2) {
        #pragma unroll
        for (int t = 0; t < 2; ++t) {
            int p = p0 + t * 16 + lq; if (p > 999) p = 999;
            qA[t] = *(const short8_t*)&Q[(((size_t)bh * 1000 + p) << 4) + quad * 8];
        }
    }
    short8_t onesB = { (short)0x3F80, (short)0x3F80, (short)0x3F80, (short)0x3F80,
                       (short)0x3F80, (short)0x3F80, (short)0x3F80, (short)0x3F80 };

    f32x4 o[2] = { {0.f,0.f,0.f,0.f}, {0.f,0.f,0.f,0.f} };
    f32x4 l[2] = { {0.f,0.f,0.f,0.f}, {0.f,0.f,0.f,0.f} };

    // mask row base pointers (no lane column folded in)
    const float* mbase[2][4];
    #pragma unroll
    for (int t = 0; t < 2; ++t)
        #pragma unroll
        for (int r = 0; r < 4; ++r) {
            int p = p0 + t * 16 + quad * 4 + r; if (p > 999) p = 999;
            mbase[t][r] = mask + ((size_t)b * 1000 + p) * 1000;
        }

    // ---- prologue: load iteration n0=0 into "current" regs
    short8_t kB0c = {}, kB1c = {};
    if (quad < 2) {
        kB0c = *(const short8_t*)&K[(((size_t)bh * 1000 + lq) << 4) + quad * 8];
        kB1c = *(const short8_t*)&K[(((size_t)bh * 1000 + 16 + lq) << 4) + quad * 8];
    }
    short8_t vBc = *(const short8_t*)&Vt[(((size_t)bh * 16 + lq) << 10) + quad * 8];
    float mkc[2][8];
    #pragma unroll
    for (int t = 0; t < 2; ++t)
        #pragma unroll
        for (int r = 0; r < 4; ++r) {
            mkc[t][r]     = mbase[t][r][lq];
            mkc[t][4 + r] = mbase[t][r][16 + lq];
        }

    // ---- main loop: keys 0..991 (31 iters), prefetching n0+32
    for (int n0 = 0; n0 < 992; n0 += 32) {
        // prefetch next iteration (clamped at the very end)
        int c0 = n0 + 32 + lq;      if (c0 > 999) c0 = 999;
        int c1 = n0 + 48 + lq;      if (c1 > 999) c1 = 999;
        short8_t kB0n = {}, kB1n = {};
        if (quad < 2) {
            kB0n = *(const short8_t*)&K[(((size_t)bh * 1000 + c0) << 4) + quad * 8];
            kB1n = *(const short8_t*)&K[(((size_t)bh * 1000 + c1) << 4) + quad * 8];
        }
        short8_t vBn = *(const short8_t*)&Vt[(((size_t)bh * 16 + lq) << 10) + n0 + 32 + quad * 8];
        float mkn[2][8];
        #pragma unroll
        for (int t = 0; t < 2; ++t)
            #pragma unroll
            for (int r = 0; r < 4; ++r) {
                mkn[t][r]     = mbase[t][r][c0];
                mkn[t][4 + r] = mbase[t][r][c1];
            }

        // compute current iteration entirely from registers
        #pragma unroll
        for (int t = 0; t < 2; ++t) {
            f32x4 zero = {0.f, 0.f, 0.f, 0.f};
            f32x4 s0 = mfma16(qA[t], kB0c, zero);
            f32x4 s1 = mfma16(qA[t], kB1c, zero);
            float e0[4], e1[4];
            #pragma unroll
            for (int r = 0; r < 4; ++r) {
                e0[r] = __expf(fmaf(s0[r], INV_SQRT_D, mkc[t][r]));
                e1[r] = __expf(fmaf(s1[r], INV_SQRT_D, mkc[t][4 + r]));
            }
            __threadfence_block();   // prior reads of this buffer done
            #pragma unroll
            for (int r = 0; r < 4; ++r)
                Plds[wave][t][quad * 4 + r][lq] = pack_bf16(e0[r], e1[r]);
            __threadfence_block();   // writes visible before read-back
            uint4 u4 = *(const uint4*)&Plds[wave][t][lq][quad * 4];
            short8_t aP = __builtin_bit_cast(short8_t, u4);
            o[t] = mfma16(aP, vBc, o[t]);
            l[t] = mfma16(aP, onesB, l[t]);
        }

        // rotate
        kB0c = kB0n; kB1c = kB1n; vBc = vBn;
        #pragma unroll
        for (int t = 0; t < 2; ++t)
            #pragma unroll
            for (int j = 0; j < 8; ++j) mkc[t][j] = mkn[t][j];
    }

    // ---- tail: keys 992..999 (8 valid; kB0c rows were clamped, vBc pads=0)
    #pragma unroll
    for (int t = 0; t < 2; ++t) {
        f32x4 zero = {0.f, 0.f, 0.f, 0.f};
        f32x4 s0 = mfma16(qA[t], kB0c, zero);
        float e0[4];
        #pragma unroll
        for (int r = 0; r < 4; ++r)
            e0[r] = (lq < 8) ? __expf(fmaf(s0[r], INV_SQRT_D, mkc[t][r])) : 0.f;
        __threadfence_block();
        #pragma unroll
        for (int r = 0; r < 4; ++r)
            Plds[wave][t][quad * 4 + r][lq] = pack_bf16(e0[r], 0.f);
        __threadfence_block();
        uint4 u4 = *(const uint4*)&Plds[wave][t][lq][quad * 4];
        short8_t aP = __builtin_bit_cast(short8_t, u4);
        o[t] = mfma16(aP, vBc, o[t]);
        l[t] = mfma16(aP, onesB, l[t]);
    }

    #pragma unroll
    for (int t = 0; t < 2; ++t)
        #pragma unroll
        for (int r = 0; r < 4; ++r) {
            int p = p0 + t * 16 + quad * 4 + r;
            if (p < 1000)
                O[((size_t)b * 1000 + p) * 128 + h * 16 + lq] = o[t][r] / l[t][r];
        }
}

// ---------------------------------------------------------------------------
// K3: MFMA combine: gated = g*(att_s@Wc_s+bc_s) + (1-g)*(att_t@Wc_t+bc_t)
// ---------------------------------------------------------------------------
__global__ __launch_bounds__(256) void combine_mfma_kernel(
    const float* __restrict__ att_s, const float* __restrict__ att_t,
    const __bf16* __restrict__ Wtb,
    const float* __restrict__ bc_s, const float* __restrict__ bc_t,
    const float* __restrict__ gate, __bf16* __restrict__ gatedb)
{
    const int wave = threadIdx.x >> 6, lane = threadIdx.x & 63;
    const int quad = lane >> 4, lq = lane & 15;
    const int r0 = blockIdx.x * 64 + wave * 16;
    const __bf16* Ws = Wtb + 126976;
    const __bf16* Wt = Wtb + 143360;

    short8_t aS[4], aT[4];
    #pragma unroll
    for (int c = 0; c < 4; ++c) {
        const float* ps = &att_s[(size_t)(r0 + lq) * 128 + c * 32 + quad * 8];
        const float* pt = &att_t[(size_t)(r0 + lq) * 128 + c * 32 + quad * 8];
        float4 x = *(const float4*)ps, y = *(const float4*)(ps + 4);
        bf16x8 s8 = { (__bf16)x.x, (__bf16)x.y, (__bf16)x.z, (__bf16)x.w,
                      (__bf16)y.x, (__bf16)y.y, (__bf16)y.z, (__bf16)y.w };
        aS[c] = __builtin_bit_cast(short8_t, s8);
        x = *(const float4*)pt; y = *(const float4*)(pt + 4);
        bf16x8 t8 = { (__bf16)x.x, (__bf16)x.y, (__bf16)x.z, (__bf16)x.w,
                      (__bf16)y.x, (__bf16)y.y, (__bf16)y.z, (__bf16)y.w };
        aT[c] = __builtin_bit_cast(short8_t, t8);
    }
    f32x4 accS[8], accT[8];
    #pragma unroll
    for (int nt = 0; nt < 8; ++nt) {
        accS[nt] = f32x4{0.f,0.f,0.f,0.f};
        accT[nt] = f32x4{0.f,0.f,0.f,0.f};
        #pragma unroll
        for (int c = 0; c < 4; ++c) {
            short8_t bS = *(const short8_t*)&Ws[(size_t)(nt * 16 + lq) * 128 + c * 32 + quad * 8];
            short8_t bT = *(const short8_t*)&Wt[(size_t)(nt * 16 + lq) * 128 + c * 32 + quad * 8];
            accS[nt] = mfma16(aS[c], bS, accS[nt]);
            accT[nt] = mfma16(aT[c], bT, accT[nt]);
        }
    }
    #pragma unroll
    for (int nt = 0; nt < 8; ++nt) {
        int f = nt * 16 + lq;
        float b1 = bc_s[f], b2 = bc_t[f];
        #pragma unroll
        for (int r = 0; r < 4; ++r) {
            int m = r0 + quad * 4 + r;
            float g = gate[(size_t)m * 128 + f];
            float val = g * (accS[nt][r] + b1) + (1.f - g) * (accT[nt][r] + b2);
            gatedb[(size_t)m * 128 + f] = (__bf16)val;
        }
    }
}

// ---------------------------------------------------------------------------
// K4: FUSED pointer scores + clip + mask + row softmax -> probs in d_out.
// Block = 16 q-rows x full N. Fully unrolled; ev[16][4] stays in VGPRs.
// ---------------------------------------------------------------------------
__global__ __launch_bounds__(256) void pointer_softmax_kernel(
    const __bf16* __restrict__ gb, const __bf16* __restrict__ nb,
    const float* __restrict__ mask, float* __restrict__ out)
{
    const int b    = blockIdx.y;
    const int p0   = blockIdx.x * 16;
    const int wave = threadIdx.x >> 6;
    const int lane = threadIdx.x & 63;
    const int quad = lane >> 4, lq = lane & 15;

    __shared__ float Spart[4][16];

    short8_t aF[4];
    {
        int pp = p0 + lq; if (pp > 999) pp = 999;
        const __bf16* arow = gb + (((size_t)b * 1000 + pp) << 7) + quad * 8;
        #pragma unroll
        for (int kc = 0; kc < 4; ++kc) aF[kc] = *(const short8_t*)&arow[kc * 32];
    }

    float ev[16][4];
    float psum[4] = {0.f, 0.f, 0.f, 0.f};

    #pragma unroll
    for (int i = 0; i < 16; ++i) {
        const int nt = i * 4 + wave;          // 0..63
        const int nn = nt * 16 + lq;
        const bool nv = nn < 1000;
        int nc = nv ? nn : 999;
        const __bf16* brow = nb + (((size_t)b * 1000 + nc) << 7) + quad * 8;
        f32x4 acc = {0.f, 0.f, 0.f, 0.f};
        #pragma unroll
        for (int kc = 0; kc < 4; ++kc) {
            short8_t bF = *(const short8_t*)&brow[kc * 32];
            acc = mfma16(aF[kc], bF, acc);
        }
        #pragma unroll
        for (int r = 0; r < 4; ++r) {
            int p = p0 + quad * 4 + r;
            bool v = nv && (p < 1000);
            size_t midx = v ? ((size_t)b * 1000 + p) * 1000 + nn : 0;
            float mk = mask[midx];
            float sc = 10.f * tanh_fast(acc[r] * INV_SQRT_E);
            float ee = v ? __expf(sc + mk) : 0.f;
            ev[i][r] = ee;
            psum[r] += ee;
        }
    }

    #pragma unroll
    for (int r = 0; r < 4; ++r) psum[r] = sum16(psum[r]);
    if (lq == 0) {
        #pragma unroll
        for (int r = 0; r < 4; ++r) Spart[wave][quad * 4 + r] = psum[r];
    }
    __syncthreads();
    float inv[4];
    #pragma unroll
    for (int r = 0; r < 4; ++r) {
        int row = quad * 4 + r;
        float s = Spart[0][row] + Spart[1][row] + Spart[2][row] + Spart[3][row];
        inv[r] = 1.f / s;
    }

    #pragma unroll
    for (int i = 0; i < 16; ++i) {
        const int nt = i * 4 + wave;
        const int nn = nt * 16 + lq;
        if (nn < 1000) {
            #pragma unroll
            for (int r = 0; r < 4; ++r) {
                int p = p0 + quad * 4 + r;
                if (p < 1000)
                    out[((size_t)b * 1000 + p) * 1000 + nn] = ev[i][r] * inv[r];
            }
        }
    }
}

// ---------------------------------------------------------------------------
extern "C" void kernel_launch(void* const* d_in, const int* in_sizes, int n_in,
                              void* d_out, int out_size, void* d_ws, size_t ws_size,
                              hipStream_t stream)
{
    const float* eln   = (const float*)d_in[0];
    const float* attr  = (const float*)d_in[1];
    const float* nodes = (const float*)d_in[2];
    const float* mask  = (const float*)d_in[3];
    const float* Wq_s  = (const float*)d_in[4];
    const float* Wk_s  = (const float*)d_in[5];
    const float* Wv_s  = (const float*)d_in[6];
    const float* Wq_t  = (const float*)d_in[7];
    const float* Wk_t  = (const float*)d_in[8];
    const float* Wv_t  = (const float*)d_in[9];
    const float* Wc_s  = (const float*)d_in[10];
    const float* bc_s  = (const float*)d_in[11];
    const float* Wc_t  = (const float*)d_in[12];
    const float* bc_t  = (const float*)d_in[13];
    const float* Wg    = (const float*)d_in[14];
    const float* bg    = (const float*)d_in[15];
    float* out = (float*)d_out;

    char* w = (char*)d_ws;
    const size_t KB_SZ = (size_t)8 * 8 * 1000 * 16 * 2;   // 2,048,000 B
    const size_t VT_SZ = (size_t)8 * 8 * 16 * 1024 * 2;   // 2,097,152 B
    const size_t F_SZ  = (size_t)8000 * 128 * 4;          // 4,096,000 B
    const size_t H_SZ  = (size_t)8000 * 128 * 2;          // 2,048,000 B
    const size_t IN_SZ = (size_t)8000 * 160 * 2;          // 2,560,000 B
    __bf16* kb_s = (__bf16*)w;            w += KB_SZ;
    __bf16* kb_t = (__bf16*)w;            w += KB_SZ;
    __bf16* qb_s = (__bf16*)w;            w += KB_SZ;
    __bf16* qb_t = (__bf16*)w;            w += KB_SZ;
    __bf16* vt_s = (__bf16*)w;            w += VT_SZ;
    __bf16* vt_t = (__bf16*)w;            w += VT_SZ;
    float* gate  = (float*)w;             w += F_SZ;
    float* att_s = (float*)w;             w += F_SZ;
    float* att_t = (float*)w;             w += F_SZ;
    __bf16* gatedb = (__bf16*)w;          w += H_SZ;
    __bf16* nodesb = (__bf16*)w;          w += H_SZ;
    __bf16* inb    = (__bf16*)w;          w += IN_SZ;
    __bf16* Wtb    = (__bf16*)w;          w += 320000;

    // zero V-transposed pads so tail B-frags are exact zeros
    hipMemsetAsync(vt_s, 0, 2 * VT_SZ, stream);

    conv_w_kernel<<<dim3(9, 5), 256, 0, stream>>>(
        Wk_s, Wv_s, Wk_t, Wv_t, Wq_s, Wq_t, Wg, Wc_s, Wc_t, Wtb);
    to_bf16_kernel<<<dim3(1000), 256, 0, stream>>>(nodes, nodesb);
    concat_inb_kernel<<<dim3(625), 256, 0, stream>>>(eln, attr, inb);
    proj_mfma_kernel<<<dim3(125, 7), 256, 0, stream>>>(
        nodesb, inb, Wtb, bg, kb_s, vt_s, kb_t, vt_t, qb_s, qb_t, gate);
    attn_mfma_kernel<<<dim3(32, 4, 8), 256, 0, stream>>>(
        qb_s, qb_t, kb_s, kb_t, vt_s, vt_t, mask, att_s, att_t);
    combine_mfma_kernel<<<dim3(125), 256, 0, stream>>>(
        att_s, att_t, Wtb, bc_s, bc_t, gate, gatedb);
    pointer_softmax_kernel<<<dim3(63, 8), 256, 0, stream>>>(
        gatedb, nodesb, mask, out);
}

// Round 7
// 242.070 us; speedup vs baseline: 1.2641x; 1.0327x over previous
//
#include <hip/hip_runtime.h>
#include <math.h>

#define BB 8
#define PP 1000
#define NN 1000
#define EE 128
#define HH 8
#define DD 16

#define INV_SQRT_E 0.08838834764831845f   // 1/sqrt(128)
#define INV_SQRT_D 0.25f                   // 1/sqrt(16)

typedef short short8_t __attribute__((ext_vector_type(8)));
typedef float f32x4    __attribute__((ext_vector_type(4)));
typedef float f32x16   __attribute__((ext_vector_type(16)));
typedef __bf16 bf16x4  __attribute__((ext_vector_type(4)));
typedef __bf16 bf16x8  __attribute__((ext_vector_type(8)));

__device__ __forceinline__ float sigmoid_fast(float x) {
    return 1.f / (1.f + __expf(-x));
}
__device__ __forceinline__ float tanh_fast(float x) {
    x = fminf(fmaxf(x, -15.f), 15.f);
    float e = __expf(2.f * x);
    return (e - 1.f) / (e + 1.f);
}

__device__ __forceinline__ f32x4 mfma16(short8_t a, short8_t b, f32x4 c) {
    return __builtin_amdgcn_mfma_f32_16x16x32_bf16(a, b, c, 0, 0, 0);
}
__device__ __forceinline__ f32x16 mfma32(short8_t a, short8_t b, f32x16 c) {
    return __builtin_amdgcn_mfma_f32_32x32x16_bf16(a, b, c, 0, 0, 0);
}

// sum across the 16 lanes of a DPP row (pure VALU butterfly)
__device__ __forceinline__ float sum16(float x) {
    int v;
    v = __builtin_amdgcn_update_dpp(0, __builtin_bit_cast(int, x), 0xB1, 0xF, 0xF, true);
    x += __builtin_bit_cast(float, v);
    v = __builtin_amdgcn_update_dpp(0, __builtin_bit_cast(int, x), 0x4E, 0xF, 0xF, true);
    x += __builtin_bit_cast(float, v);
    v = __builtin_amdgcn_update_dpp(0, __builtin_bit_cast(int, x), 0x141, 0xF, 0xF, true);
    x += __builtin_bit_cast(float, v);
    v = __builtin_amdgcn_update_dpp(0, __builtin_bit_cast(int, x), 0x140, 0xF, 0xF, true);
    x += __builtin_bit_cast(float, v);
    return x;
}

__device__ __forceinline__ unsigned int pack_bf16(float a, float b) {
    __bf16 x = (__bf16)a, y = (__bf16)b;
    unsigned short ux = __builtin_bit_cast(unsigned short, x);
    unsigned short uy = __builtin_bit_cast(unsigned short, y);
    return (unsigned int)ux | ((unsigned int)uy << 16);
}

// ---------------------------------------------------------------------------
// K0a: weights -> transposed bf16 Wtb via LDS-tiled transpose (coalesced both
// ways). layout Wt[n][k] (k padded), offsets as in proj kernel.
// ---------------------------------------------------------------------------
__global__ __launch_bounds__(256) void conv_w_kernel(
    const float* __restrict__ Wk_s, const float* __restrict__ Wv_s,
    const float* __restrict__ Wk_t, const float* __restrict__ Wv_t,
    const float* __restrict__ Wq_s, const float* __restrict__ Wq_t,
    const float* __restrict__ Wg,   const float* __restrict__ Wc_s,
    const float* __restrict__ Wc_t, __bf16* __restrict__ Wtb)
{
    const int m = blockIdx.x, kt = blockIdx.y;
    const float* srcs[9] = {Wk_s, Wv_s, Wk_t, Wv_t, Wq_s, Wq_t, Wg, Wc_s, Wc_t};
    const int   srcKs[9] = {128, 128, 128, 128, 132, 132, 132, 128, 128};
    const int   kpads[9] = {128, 128, 128, 128, 160, 160, 160, 128, 128};
    const size_t offs[9] = {0, 16384, 32768, 49152, 65536, 86016, 106496, 126976, 143360};
    const int kp = kpads[m];
    if (kt * 32 >= kp) return;
    const float* src = srcs[m];
    const int sK = srcKs[m];
    const size_t off = offs[m];
    __shared__ float tile[32][129];
    const int tid = threadIdx.x;
    for (int j = tid; j < 32 * 128; j += 256) {
        int kk = j >> 7, n = j & 127;
        int k = kt * 32 + kk;
        tile[kk][n] = (k < sK) ? src[(size_t)k * 128 + n] : 0.f;
    }
    __syncthreads();
    for (int j = tid; j < 32 * 128; j += 256) {
        int n = j >> 5, kk = j & 31;
        Wtb[off + (size_t)n * kp + kt * 32 + kk] = (__bf16)tile[kk][n];
    }
}

// ---------------------------------------------------------------------------
// K0b: nodes fp32 -> bf16 [8000][128]
// ---------------------------------------------------------------------------
__global__ __launch_bounds__(256) void to_bf16_kernel(
    const float* __restrict__ in, __bf16* __restrict__ outb)
{
    int i = (blockIdx.x * 256 + threadIdx.x) * 4;
    float4 v = *(const float4*)&in[i];
    bf16x4 pk = { (__bf16)v.x, (__bf16)v.y, (__bf16)v.z, (__bf16)v.w };
    *(bf16x4*)&outb[i] = pk;
}

// ---------------------------------------------------------------------------
// K0c: inb[8000][160] = concat(eln[128], attr[4], zeros[28]) in bf16
// ---------------------------------------------------------------------------
__global__ __launch_bounds__(256) void concat_inb_kernel(
    const float* __restrict__ eln, const float* __restrict__ attr,
    __bf16* __restrict__ inb)
{
    int t = blockIdx.x * 256 + threadIdx.x;
    int row = t / 20, seg = t - row * 20;
    bf16x8 o = {};
    if (seg < 16) {
        const float* p = &eln[(size_t)row * 128 + seg * 8];
        float4 a = *(const float4*)p, b = *(const float4*)(p + 4);
        o = bf16x8{ (__bf16)a.x, (__bf16)a.y, (__bf16)a.z, (__bf16)a.w,
                    (__bf16)b.x, (__bf16)b.y, (__bf16)b.z, (__bf16)b.w };
    } else if (seg == 16) {
        float4 a = *(const float4*)&attr[(size_t)row * 4];
        o = bf16x8{ (__bf16)a.x, (__bf16)a.y, (__bf16)a.z, (__bf16)a.w,
                    (__bf16)0.f, (__bf16)0.f, (__bf16)0.f, (__bf16)0.f };
    }
    *(bf16x8*)&inb[(size_t)row * 160 + seg * 8] = o;
}

// ---------------------------------------------------------------------------
// K1: MFMA projections. Wave = 16 rows x 128 cols. blockIdx.y = wsel:
// 0..3 kv (A=nodesb,K=128), 4..5 q (A=inb,K=160), 6 gate (A=inb,K=160).
// ---------------------------------------------------------------------------
template<int NC>
__device__ __forceinline__ void proj_body(
    const __bf16* __restrict__ A, const __bf16* __restrict__ W,
    f32x4 acc[8], int r0, int quad, int lq)
{
    const int K = NC * 32;
    short8_t aF[NC];
    #pragma unroll
    for (int c = 0; c < NC; ++c)
        aF[c] = *(const short8_t*)&A[(size_t)(r0 + lq) * K + c * 32 + quad * 8];
    #pragma unroll
    for (int nt = 0; nt < 8; ++nt) {
        acc[nt] = f32x4{0.f, 0.f, 0.f, 0.f};
        #pragma unroll
        for (int c = 0; c < NC; ++c) {
            short8_t bF = *(const short8_t*)&W[(size_t)(nt * 16 + lq) * K + c * 32 + quad * 8];
            acc[nt] = mfma16(aF[c], bF, acc[nt]);
        }
    }
}

__global__ __launch_bounds__(256) void proj_mfma_kernel(
    const __bf16* __restrict__ nodesb, const __bf16* __restrict__ inb,
    const __bf16* __restrict__ Wtb, const float* __restrict__ bg,
    __bf16* __restrict__ kb_s, __bf16* __restrict__ vt_s,
    __bf16* __restrict__ kb_t, __bf16* __restrict__ vt_t,
    __bf16* __restrict__ qb_s, __bf16* __restrict__ qb_t,
    float* __restrict__ gate)
{
    const int wsel = blockIdx.y;
    const int wave = threadIdx.x >> 6, lane = threadIdx.x & 63;
    const int quad = lane >> 4, lq = lane & 15;
    const int r0 = blockIdx.x * 64 + wave * 16;

    f32x4 acc[8];
    if (wsel < 4) {
        proj_body<4>(nodesb, Wtb + (size_t)wsel * 16384, acc, r0, quad, lq);
    } else {
        proj_body<5>(inb, Wtb + 65536 + (size_t)(wsel - 4) * 20480, acc, r0, quad, lq);
    }

    if (wsel == 0 || wsel == 2 || wsel == 4 || wsel == 5) {
        __bf16* O = (wsel == 0) ? kb_s : (wsel == 2) ? kb_t : (wsel == 4) ? qb_s : qb_t;
        #pragma unroll
        for (int r = 0; r < 4; ++r) {
            int m = r0 + quad * 4 + r;
            int b = m / 1000, n = m - b * 1000;
            #pragma unroll
            for (int nt = 0; nt < 8; ++nt)
                O[(((size_t)(b * 8 + nt) * 1000 + n) << 4) + lq] = (__bf16)acc[nt][r];
        }
    } else if (wsel == 1 || wsel == 3) {
        __bf16* O = (wsel == 1) ? vt_s : vt_t;
        #pragma unroll
        for (int r = 0; r < 4; ++r) {
            int m = r0 + quad * 4 + r;
            int b = m / 1000, n = m - b * 1000;
            int rr = n & 31;
            int pos = (n & ~31) + ((rr < 16) ? (rr << 1) : (((rr - 16) << 1) | 1));
            #pragma unroll
            for (int nt = 0; nt < 8; ++nt)
                O[(((size_t)(b * 8 + nt) * 16 + lq) << 10) + pos] = (__bf16)acc[nt][r];
        }
    } else {
        #pragma unroll
        for (int nt = 0; nt < 8; ++nt) {
            float bias = bg[nt * 16 + lq];
            #pragma unroll
            for (int r = 0; r < 4; ++r) {
                int m = r0 + quad * 4 + r;
                gate[(size_t)m * 128 + nt * 16 + lq] = sigmoid_fast(acc[nt][r] + bias);
            }
        }
    }
}

// ---------------------------------------------------------------------------
// K2: MFMA flash attention v3. One wave = one (b,h,br) x 32-query tile.
// QK via ONE 32x32x16 MFMA (K=16=D, no padding). Mask loaded in 32x32
// C-layout (fully coalesced 128B rows, 8 row-pair pointers). Scores exp'd in
// C-layout, bf16 through LDS (C->A transform), interleaved into PV A-frag
// with v_perm. PV + l via 16x16x32 MFMA against permuted V / ones.
// ---------------------------------------------------------------------------
__global__ __launch_bounds__(256) void attn_mfma_kernel(
    const __bf16* __restrict__ qb_s, const __bf16* __restrict__ qb_t,
    const __bf16* __restrict__ kb_s, const __bf16* __restrict__ kb_t,
    const __bf16* __restrict__ vt_s, const __bf16* __restrict__ vt_t,
    const float* __restrict__ mask,
    float* __restrict__ att_s, float* __restrict__ att_t)
{
    const int b    = blockIdx.z;
    const int wave = threadIdx.x >> 6;
    const int combo = blockIdx.y * 4 + wave;
    const int br = combo & 1;
    const int h  = combo >> 1;
    const __bf16* Q  = br ? qb_t : qb_s;
    const __bf16* K  = br ? kb_t : kb_s;
    const __bf16* Vt = br ? vt_t : vt_s;
    float* O         = br ? att_t : att_s;
    const int lane = threadIdx.x & 63;
    const int quad = lane >> 4, lq = lane & 15;
    const int col  = lane & 31;         // 32x32 column (key)
    const int half = lane >> 5;         // 32x32 row-half
    const int bh = b * HH + h;
    const int p0 = blockIdx.x * 32;

    __shared__ __align__(16) __bf16 S[4][32][36];   // per-wave 32x32 scores (+pad)

    // Q A-frag (32x32x16): m = col (query), k = 8*half + j
    int pq = p0 + col; if (pq > 999) pq = 999;
    short8_t qA = *(const short8_t*)&Q[(((size_t)bh * 1000 + pq) << 4) + half * 8];

    short8_t onesB = { (short)0x3F80, (short)0x3F80, (short)0x3F80, (short)0x3F80,
                       (short)0x3F80, (short)0x3F80, (short)0x3F80, (short)0x3F80 };

    f32x4 o[2] = { {0.f,0.f,0.f,0.f}, {0.f,0.f,0.f,0.f} };
    f32x4 l[2] = { {0.f,0.f,0.f,0.f}, {0.f,0.f,0.f,0.f} };

    // 8 mask row-pair pointers: pair j covers C rows {2j, 2j+1} of this lane's
    // half. row(reg) = (reg&3) + 8*(reg>>2) + 4*half; regs (2j,2j+1) are
    // consecutive rows, second accessed via +1000 element immediate offset.
    const float* mrow[8];
    #pragma unroll
    for (int j = 0; j < 8; ++j) {
        int row = p0 + ((2 * j) & 3) + 8 * (j >> 1) + 4 * half;
        if (row > 998) row = 998;       // keep row+1 in-bounds; garbage discarded
        mrow[j] = mask + ((size_t)b * 1000 + row) * 1000 + col;
    }

    // prologue: K/V frags for keys 0..31
    short8_t kBc = *(const short8_t*)&K[(((size_t)bh * 1000 + col) << 4) + half * 8];
    short8_t vBc = *(const short8_t*)&Vt[(((size_t)bh * 16 + lq) << 10) + quad * 8];

    for (int n0 = 0; n0 < 992; n0 += 32) {
        // ---- prefetch next K/V (clamped at the end)
        int nk = n0 + 32 + col; if (nk > 999) nk = 999;
        short8_t kBn = *(const short8_t*)&K[(((size_t)bh * 1000 + nk) << 4) + half * 8];
        short8_t vBn = *(const short8_t*)&Vt[(((size_t)bh * 16 + lq) << 10) + n0 + 32 + quad * 8];

        // ---- mask for current 32 keys (coalesced 128B rows)
        float mk[16];
        #pragma unroll
        for (int j = 0; j < 8; ++j) {
            mk[2 * j]     = mrow[j][0];
            mk[2 * j + 1] = mrow[j][1000];
            mrow[j] += 32;
        }

        // ---- QK: one 32x32x16 MFMA
        f32x16 s = mfma32(qA, kBc, f32x16{});

        // ---- exp in C-layout -> bf16 LDS
        __threadfence_block();
        #pragma unroll
        for (int reg = 0; reg < 16; ++reg) {
            float e = __expf(fmaf(s[reg], INV_SQRT_D, mk[reg]));
            S[wave][(reg & 3) + 8 * (reg >> 2) + 4 * half][col] = (__bf16)e;
        }
        __threadfence_block();

        // ---- per 16-query tile: read A-frag halves, interleave, PV + l
        #pragma unroll
        for (int t = 0; t < 2; ++t) {
            uint2 L = *(const uint2*)&S[wave][t * 16 + lq][quad * 4];
            uint2 H = *(const uint2*)&S[wave][t * 16 + lq][16 + quad * 4];
            unsigned u0 = __builtin_amdgcn_perm(H.x, L.x, 0x05040100u);
            unsigned u1 = __builtin_amdgcn_perm(H.x, L.x, 0x07060302u);
            unsigned u2 = __builtin_amdgcn_perm(H.y, L.y, 0x05040100u);
            unsigned u3 = __builtin_amdgcn_perm(H.y, L.y, 0x07060302u);
            uint4 u4 = make_uint4(u0, u1, u2, u3);
            short8_t aP = __builtin_bit_cast(short8_t, u4);
            o[t] = mfma16(aP, vBc, o[t]);
            l[t] = mfma16(aP, onesB, l[t]);
        }
        kBc = kBn; vBc = vBn;
    }

    // ---- tail: keys 992..999 (valid iff col < 8); kBc clamped, vBc zero-pad
    {
        f32x16 s = mfma32(qA, kBc, f32x16{});
        __threadfence_block();
        #pragma unroll
        for (int reg = 0; reg < 16; ++reg) {
            int j = reg >> 1;
            float mkv = (col < 8) ? ((reg & 1) ? mrow[j][1000] : mrow[j][0]) : 0.f;
            float e = (col < 8) ? __expf(fmaf(s[reg], INV_SQRT_D, mkv)) : 0.f;
            S[wave][(reg & 3) + 8 * (reg >> 2) + 4 * half][col] = (__bf16)e;
        }
        __threadfence_block();
        #pragma unroll
        for (int t = 0; t < 2; ++t) {
            uint2 L = *(const uint2*)&S[wave][t * 16 + lq][quad * 4];
            uint2 H = *(const uint2*)&S[wave][t * 16 + lq][16 + quad * 4];
            unsigned u0 = __builtin_amdgcn_perm(H.x, L.x, 0x05040100u);
            unsigned u1 = __builtin_amdgcn_perm(H.x, L.x, 0x07060302u);
            unsigned u2 = __builtin_amdgcn_perm(H.y, L.y, 0x05040100u);
            unsigned u3 = __builtin_amdgcn_perm(H.y, L.y, 0x07060302u);
            uint4 u4 = make_uint4(u0, u1, u2, u3);
            short8_t aP = __builtin_bit_cast(short8_t, u4);
            o[t] = mfma16(aP, vBc, o[t]);
            l[t] = mfma16(aP, onesB, l[t]);
        }
    }

    #pragma unroll
    for (int t = 0; t < 2; ++t)
        #pragma unroll
        for (int r = 0; r < 4; ++r) {
            int p = p0 + t * 16 + quad * 4 + r;
            if (p < 1000)
                O[((size_t)b * 1000 + p) * 128 + h * 16 + lq] = o[t][r] / l[t][r];
        }
}

// ---------------------------------------------------------------------------
// K3: MFMA combine: gated = g*(att_s@Wc_s+bc_s) + (1-g)*(att_t@Wc_t+bc_t)
// ---------------------------------------------------------------------------
__global__ __launch_bounds__(256) void combine_mfma_kernel(
    const float* __restrict__ att_s, const float* __restrict__ att_t,
    const __bf16* __restrict__ Wtb,
    const float* __restrict__ bc_s, const float* __restrict__ bc_t,
    const float* __restrict__ gate, __bf16* __restrict__ gatedb)
{
    const int wave = threadIdx.x >> 6, lane = threadIdx.x & 63;
    const int quad = lane >> 4, lq = lane & 15;
    const int r0 = blockIdx.x * 64 + wave * 16;
    const __bf16* Ws = Wtb + 126976;
    const __bf16* Wt = Wtb + 143360;

    short8_t aS[4], aT[4];
    #pragma unroll
    for (int c = 0; c < 4; ++c) {
        const float* ps = &att_s[(size_t)(r0 + lq) * 128 + c * 32 + quad * 8];
        const float* pt = &att_t[(size_t)(r0 + lq) * 128 + c * 32 + quad * 8];
        float4 x = *(const float4*)ps, y = *(const float4*)(ps + 4);
        bf16x8 s8 = { (__bf16)x.x, (__bf16)x.y, (__bf16)x.z, (__bf16)x.w,
                      (__bf16)y.x, (__bf16)y.y, (__bf16)y.z, (__bf16)y.w };
        aS[c] = __builtin_bit_cast(short8_t, s8);
        x = *(const float4*)pt; y = *(const float4*)(pt + 4);
        bf16x8 t8 = { (__bf16)x.x, (__bf16)x.y, (__bf16)x.z, (__bf16)x.w,
                      (__bf16)y.x, (__bf16)y.y, (__bf16)y.z, (__bf16)y.w };
        aT[c] = __builtin_bit_cast(short8_t, t8);
    }
    f32x4 accS[8], accT[8];
    #pragma unroll
    for (int nt = 0; nt < 8; ++nt) {
        accS[nt] = f32x4{0.f,0.f,0.f,0.f};
        accT[nt] = f32x4{0.f,0.f,0.f,0.f};
        #pragma unroll
        for (int c = 0; c < 4; ++c) {
            short8_t bS = *(const short8_t*)&Ws[(size_t)(nt * 16 + lq) * 128 + c * 32 + quad * 8];
            short8_t bT = *(const short8_t*)&Wt[(size_t)(nt * 16 + lq) * 128 + c * 32 + quad * 8];
            accS[nt] = mfma16(aS[c], bS, accS[nt]);
            accT[nt] = mfma16(aT[c], bT, accT[nt]);
        }
    }
    #pragma unroll
    for (int nt = 0; nt < 8; ++nt) {
        int f = nt * 16 + lq;
        float b1 = bc_s[f], b2 = bc_t[f];
        #pragma unroll
        for (int r = 0; r < 4; ++r) {
            int m = r0 + quad * 4 + r;
            float g = gate[(size_t)m * 128 + f];
            float val = g * (accS[nt][r] + b1) + (1.f - g) * (accT[nt][r] + b2);
            gatedb[(size_t)m * 128 + f] = (__bf16)val;
        }
    }
}

// ---------------------------------------------------------------------------
// K4: FUSED pointer scores + clip + mask + row softmax -> probs in d_out.
// Block = 16 q-rows x full N. Fully unrolled; ev[16][4] stays in VGPRs.
// ---------------------------------------------------------------------------
__global__ __launch_bounds__(256) void pointer_softmax_kernel(
    const __bf16* __restrict__ gb, const __bf16* __restrict__ nb,
    const float* __restrict__ mask, float* __restrict__ out)
{
    const int b    = blockIdx.y;
    const int p0   = blockIdx.x * 16;
    const int wave = threadIdx.x >> 6;
    const int lane = threadIdx.x & 63;
    const int quad = lane >> 4, lq = lane & 15;

    __shared__ float Spart[4][16];

    short8_t aF[4];
    {
        int pp = p0 + lq; if (pp > 999) pp = 999;
        const __bf16* arow = gb + (((size_t)b * 1000 + pp) << 7) + quad * 8;
        #pragma unroll
        for (int kc = 0; kc < 4; ++kc) aF[kc] = *(const short8_t*)&arow[kc * 32];
    }

    float ev[16][4];
    float psum[4] = {0.f, 0.f, 0.f, 0.f};

    #pragma unroll
    for (int i = 0; i < 16; ++i) {
        const int nt = i * 4 + wave;          // 0..63
        const int nn = nt * 16 + lq;
        const bool nv = nn < 1000;
        int nc = nv ? nn : 999;
        const __bf16* brow = nb + (((size_t)b * 1000 + nc) << 7) + quad * 8;
        f32x4 acc = {0.f, 0.f, 0.f, 0.f};
        #pragma unroll
        for (int kc = 0; kc < 4; ++kc) {
            short8_t bF = *(const short8_t*)&brow[kc * 32];
            acc = mfma16(aF[kc], bF, acc);
        }
        #pragma unroll
        for (int r = 0; r < 4; ++r) {
            int p = p0 + quad * 4 + r;
            bool v = nv && (p < 1000);
            size_t midx = v ? ((size_t)b * 1000 + p) * 1000 + nn : 0;
            float mk = mask[midx];
            float sc = 10.f * tanh_fast(acc[r] * INV_SQRT_E);
            float ee = v ? __expf(sc + mk) : 0.f;
            ev[i][r] = ee;
            psum[r] += ee;
        }
    }

    #pragma unroll
    for (int r = 0; r < 4; ++r) psum[r] = sum16(psum[r]);
    if (lq == 0) {
        #pragma unroll
        for (int r = 0; r < 4; ++r) Spart[wave][quad * 4 + r] = psum[r];
    }
    __syncthreads();
    float inv[4];
    #pragma unroll
    for (int r = 0; r < 4; ++r) {
        int row = quad * 4 + r;
        float s = Spart[0][row] + Spart[1][row] + Spart[2][row] + Spart[3][row];
        inv[r] = 1.f / s;
    }

    #pragma unroll
    for (int i = 0; i < 16; ++i) {
        const int nt = i * 4 + wave;
        const int nn = nt * 16 + lq;
        if (nn < 1000) {
            #pragma unroll
            for (int r = 0; r < 4; ++r) {
                int p = p0 + quad * 4 + r;
                if (p < 1000)
                    out[((size_t)b * 1000 + p) * 1000 + nn] = ev[i][r] * inv[r];
            }
        }
    }
}

// ---------------------------------------------------------------------------
extern "C" void kernel_launch(void* const* d_in, const int* in_sizes, int n_in,
                              void* d_out, int out_size, void* d_ws, size_t ws_size,
                              hipStream_t stream)
{
    const float* eln   = (const float*)d_in[0];
    const float* attr  = (const float*)d_in[1];
    const float* nodes = (const float*)d_in[2];
    const float* mask  = (const float*)d_in[3];
    const float* Wq_s  = (const float*)d_in[4];
    const float* Wk_s  = (const float*)d_in[5];
    const float* Wv_s  = (const float*)d_in[6];
    const float* Wq_t  = (const float*)d_in[7];
    const float* Wk_t  = (const float*)d_in[8];
    const float* Wv_t  = (const float*)d_in[9];
    const float* Wc_s  = (const float*)d_in[10];
    const float* bc_s  = (const float*)d_in[11];
    const float* Wc_t  = (const float*)d_in[12];
    const float* bc_t  = (const float*)d_in[13];
    const float* Wg    = (const float*)d_in[14];
    const float* bg    = (const float*)d_in[15];
    float* out = (float*)d_out;

    char* w = (char*)d_ws;
    const size_t KB_SZ = (size_t)8 * 8 * 1000 * 16 * 2;   // 2,048,000 B
    const size_t VT_SZ = (size_t)8 * 8 * 16 * 1024 * 2;   // 2,097,152 B
    const size_t F_SZ  = (size_t)8000 * 128 * 4;          // 4,096,000 B
    const size_t H_SZ  = (size_t)8000 * 128 * 2;          // 2,048,000 B
    const size_t IN_SZ = (size_t)8000 * 160 * 2;          // 2,560,000 B
    __bf16* kb_s = (__bf16*)w;            w += KB_SZ;
    __bf16* kb_t = (__bf16*)w;            w += KB_SZ;
    __bf16* qb_s = (__bf16*)w;            w += KB_SZ;
    __bf16* qb_t = (__bf16*)w;            w += KB_SZ;
    __bf16* vt_s = (__bf16*)w;            w += VT_SZ;
    __bf16* vt_t = (__bf16*)w;            w += VT_SZ;
    float* gate  = (float*)w;             w += F_SZ;
    float* att_s = (float*)w;             w += F_SZ;
    float* att_t = (float*)w;             w += F_SZ;
    __bf16* gatedb = (__bf16*)w;          w += H_SZ;
    __bf16* nodesb = (__bf16*)w;          w += H_SZ;
    __bf16* inb    = (__bf16*)w;          w += IN_SZ;
    __bf16* Wtb    = (__bf16*)w;          w += 320000;

    // zero V-transposed pads so tail B-frags are exact zeros
    hipMemsetAsync(vt_s, 0, 2 * VT_SZ, stream);

    conv_w_kernel<<<dim3(9, 5), 256, 0, stream>>>(
        Wk_s, Wv_s, Wk_t, Wv_t, Wq_s, Wq_t, Wg, Wc_s, Wc_t, Wtb);
    to_bf16_kernel<<<dim3(1000), 256, 0, stream>>>(nodes, nodesb);
    concat_inb_kernel<<<dim3(625), 256, 0, stream>>>(eln, attr, inb);
    proj_mfma_kernel<<<dim3(125, 7), 256, 0, stream>>>(
        nodesb, inb, Wtb, bg, kb_s, vt_s, kb_t, vt_t, qb_s, qb_t, gate);
    attn_mfma_kernel<<<dim3(32, 4, 8), 256, 0, stream>>>(
        qb_s, qb_t, kb_s, kb_t, vt_s, vt_t, mask, att_s, att_t);
    combine_mfma_kernel<<<dim3(125), 256, 0, stream>>>(
        att_s, att_t, Wtb, bc_s, bc_t, gate, gatedb);
    pointer_softmax_kernel<<<dim3(63, 8), 256, 0, stream>>>(
        gatedb, nodesb, mask, out);
}

// Round 8
// 229.208 us; speedup vs baseline: 1.3351x; 1.0561x over previous
//
#include <hip/hip_runtime.h>
#include <math.h>

#define BB 8
#define PP 1000
#define NN 1000
#define EE 128
#define HH 8
#define DD 16

#define INV_SQRT_E 0.08838834764831845f   // 1/sqrt(128)
#define INV_SQRT_D 0.25f                   // 1/sqrt(16), folded into Q at proj

typedef short short8_t __attribute__((ext_vector_type(8)));
typedef float f32x4    __attribute__((ext_vector_type(4)));
typedef float f32x16   __attribute__((ext_vector_type(16)));
typedef __bf16 bf16x4  __attribute__((ext_vector_type(4)));
typedef __bf16 bf16x8  __attribute__((ext_vector_type(8)));

__device__ __forceinline__ float sigmoid_fast(float x) {
    return 1.f / (1.f + __expf(-x));
}
__device__ __forceinline__ float tanh_fast(float x) {
    x = fminf(fmaxf(x, -15.f), 15.f);
    float e = __expf(2.f * x);
    return (e - 1.f) / (e + 1.f);
}

__device__ __forceinline__ f32x4 mfma16(short8_t a, short8_t b, f32x4 c) {
    return __builtin_amdgcn_mfma_f32_16x16x32_bf16(a, b, c, 0, 0, 0);
}
__device__ __forceinline__ f32x16 mfma32(short8_t a, short8_t b, f32x16 c) {
    return __builtin_amdgcn_mfma_f32_32x32x16_bf16(a, b, c, 0, 0, 0);
}

// sum across the 16 lanes of a DPP row (pure VALU butterfly)
__device__ __forceinline__ float sum16(float x) {
    int v;
    v = __builtin_amdgcn_update_dpp(0, __builtin_bit_cast(int, x), 0xB1, 0xF, 0xF, true);
    x += __builtin_bit_cast(float, v);
    v = __builtin_amdgcn_update_dpp(0, __builtin_bit_cast(int, x), 0x4E, 0xF, 0xF, true);
    x += __builtin_bit_cast(float, v);
    v = __builtin_amdgcn_update_dpp(0, __builtin_bit_cast(int, x), 0x141, 0xF, 0xF, true);
    x += __builtin_bit_cast(float, v);
    v = __builtin_amdgcn_update_dpp(0, __builtin_bit_cast(int, x), 0x140, 0xF, 0xF, true);
    x += __builtin_bit_cast(float, v);
    return x;
}

// ---------------------------------------------------------------------------
// K0: FUSED prep. Grid segments:
//  [0,7813)      emaskb = (bf16)exp(mask)            (8M elems)
//  [7813,8813)   nodesb = (bf16)nodes               (1.024M elems)
//  [8813,9438)   inb = concat(eln,attr,0) bf16      (8000x160)
//  [9438,9483)   Wtb = transposed bf16 weights      (9 x 5 k-tiles)
// Wtb offsets: 0:k_s 16384:v_s 32768:k_t 49152:v_t 65536:q_s 86016:q_t
//              106496:g 126976:c_s 143360:c_t
// ---------------------------------------------------------------------------
__global__ __launch_bounds__(256) void prep_kernel(
    const float* __restrict__ mask, const float* __restrict__ nodes,
    const float* __restrict__ eln,  const float* __restrict__ attr,
    const float* __restrict__ Wk_s, const float* __restrict__ Wv_s,
    const float* __restrict__ Wk_t, const float* __restrict__ Wv_t,
    const float* __restrict__ Wq_s, const float* __restrict__ Wq_t,
    const float* __restrict__ Wg,   const float* __restrict__ Wc_s,
    const float* __restrict__ Wc_t,
    __bf16* __restrict__ emaskb, __bf16* __restrict__ nodesb,
    __bf16* __restrict__ inb, __bf16* __restrict__ Wtb)
{
    const int bx = blockIdx.x;
    __shared__ float tile[32][129];
    if (bx < 7813) {
        int i = (bx * 256 + threadIdx.x) * 4;
        if (i < 8000000) {
            float4 v = *(const float4*)&mask[i];
            bf16x4 pk = { (__bf16)__expf(v.x), (__bf16)__expf(v.y),
                          (__bf16)__expf(v.z), (__bf16)__expf(v.w) };
            *(bf16x4*)&emaskb[i] = pk;
        }
    } else if (bx < 8813) {
        int i = ((bx - 7813) * 256 + threadIdx.x) * 4;
        float4 v = *(const float4*)&nodes[i];
        bf16x4 pk = { (__bf16)v.x, (__bf16)v.y, (__bf16)v.z, (__bf16)v.w };
        *(bf16x4*)&nodesb[i] = pk;
    } else if (bx < 9438) {
        int t = (bx - 8813) * 256 + threadIdx.x;
        int row = t / 20, seg = t - row * 20;
        bf16x8 o = {};
        if (seg < 16) {
            const float* p = &eln[(size_t)row * 128 + seg * 8];
            float4 a = *(const float4*)p, b = *(const float4*)(p + 4);
            o = bf16x8{ (__bf16)a.x, (__bf16)a.y, (__bf16)a.z, (__bf16)a.w,
                        (__bf16)b.x, (__bf16)b.y, (__bf16)b.z, (__bf16)b.w };
        } else if (seg == 16) {
            float4 a = *(const float4*)&attr[(size_t)row * 4];
            o = bf16x8{ (__bf16)a.x, (__bf16)a.y, (__bf16)a.z, (__bf16)a.w,
                        (__bf16)0.f, (__bf16)0.f, (__bf16)0.f, (__bf16)0.f };
        }
        *(bf16x8*)&inb[(size_t)row * 160 + seg * 8] = o;
    } else {
        int idx = bx - 9438;
        int m = idx / 5, kt = idx - m * 5;
        const float* srcs[9] = {Wk_s, Wv_s, Wk_t, Wv_t, Wq_s, Wq_t, Wg, Wc_s, Wc_t};
        const int   srcKs[9] = {128, 128, 128, 128, 132, 132, 132, 128, 128};
        const int   kpads[9] = {128, 128, 128, 128, 160, 160, 160, 128, 128};
        const size_t offs[9] = {0, 16384, 32768, 49152, 65536, 86016, 106496, 126976, 143360};
        const int kp = kpads[m];
        if (kt * 32 >= kp) return;
        const float* src = srcs[m];
        const int sK = srcKs[m];
        const size_t off = offs[m];
        const int tid = threadIdx.x;
        for (int j = tid; j < 32 * 128; j += 256) {
            int kk = j >> 7, n = j & 127;
            int k = kt * 32 + kk;
            tile[kk][n] = (k < sK) ? src[(size_t)k * 128 + n] : 0.f;
        }
        __syncthreads();
        for (int j = tid; j < 32 * 128; j += 256) {
            int n = j >> 5, kk = j & 31;
            Wtb[off + (size_t)n * kp + kt * 32 + kk] = (__bf16)tile[kk][n];
        }
    }
}

// ---------------------------------------------------------------------------
// K1: MFMA projections. Wave = 16 rows x 128 cols. blockIdx.y = wsel:
// 0..3 kv (A=nodesb,K=128), 4..5 q (A=inb,K=160, scaled by 1/sqrt(D)).
// ---------------------------------------------------------------------------
template<int NC>
__device__ __forceinline__ void proj_body(
    const __bf16* __restrict__ A, const __bf16* __restrict__ W,
    f32x4 acc[8], int r0, int quad, int lq)
{
    const int K = NC * 32;
    short8_t aF[NC];
    #pragma unroll
    for (int c = 0; c < NC; ++c)
        aF[c] = *(const short8_t*)&A[(size_t)(r0 + lq) * K + c * 32 + quad * 8];
    #pragma unroll
    for (int nt = 0; nt < 8; ++nt) {
        acc[nt] = f32x4{0.f, 0.f, 0.f, 0.f};
        #pragma unroll
        for (int c = 0; c < NC; ++c) {
            short8_t bF = *(const short8_t*)&W[(size_t)(nt * 16 + lq) * K + c * 32 + quad * 8];
            acc[nt] = mfma16(aF[c], bF, acc[nt]);
        }
    }
}

__global__ __launch_bounds__(256) void proj_mfma_kernel(
    const __bf16* __restrict__ nodesb, const __bf16* __restrict__ inb,
    const __bf16* __restrict__ Wtb,
    __bf16* __restrict__ kb_s, __bf16* __restrict__ vt_s,
    __bf16* __restrict__ kb_t, __bf16* __restrict__ vt_t,
    __bf16* __restrict__ qb_s, __bf16* __restrict__ qb_t)
{
    const int wsel = blockIdx.y;
    const int wave = threadIdx.x >> 6, lane = threadIdx.x & 63;
    const int quad = lane >> 4, lq = lane & 15;
    const int r0 = blockIdx.x * 64 + wave * 16;

    f32x4 acc[8];
    if (wsel < 4) {
        proj_body<4>(nodesb, Wtb + (size_t)wsel * 16384, acc, r0, quad, lq);
    } else {
        proj_body<5>(inb, Wtb + 65536 + (size_t)(wsel - 4) * 20480, acc, r0, quad, lq);
    }

    if (wsel == 0 || wsel == 2) {
        __bf16* O = (wsel == 0) ? kb_s : kb_t;
        #pragma unroll
        for (int r = 0; r < 4; ++r) {
            int m = r0 + quad * 4 + r;
            int b = m / 1000, n = m - b * 1000;
            #pragma unroll
            for (int nt = 0; nt < 8; ++nt)
                O[(((size_t)(b * 8 + nt) * 1000 + n) << 4) + lq] = (__bf16)acc[nt][r];
        }
    } else if (wsel == 4 || wsel == 5) {
        __bf16* O = (wsel == 4) ? qb_s : qb_t;
        #pragma unroll
        for (int r = 0; r < 4; ++r) {
            int m = r0 + quad * 4 + r;
            int b = m / 1000, n = m - b * 1000;
            #pragma unroll
            for (int nt = 0; nt < 8; ++nt)
                O[(((size_t)(b * 8 + nt) * 1000 + n) << 4) + lq] =
                    (__bf16)(acc[nt][r] * INV_SQRT_D);
        }
    } else {
        __bf16* O = (wsel == 1) ? vt_s : vt_t;
        #pragma unroll
        for (int r = 0; r < 4; ++r) {
            int m = r0 + quad * 4 + r;
            int b = m / 1000, n = m - b * 1000;
            int rr = n & 31;
            int pos = (n & ~31) + ((rr < 16) ? (rr << 1) : (((rr - 16) << 1) | 1));
            #pragma unroll
            for (int nt = 0; nt < 8; ++nt)
                O[(((size_t)(b * 8 + nt) * 16 + lq) << 10) + pos] = (__bf16)acc[nt][r];
        }
    }
}

// ---------------------------------------------------------------------------
// K2: MFMA flash attention v4: emask (pre-exponentiated bf16 mask),
// P = exp(s)*emask. Q pre-scaled by 1/sqrt(D). Output att in bf16.
// ---------------------------------------------------------------------------
__global__ __launch_bounds__(256) void attn_mfma_kernel(
    const __bf16* __restrict__ qb_s, const __bf16* __restrict__ qb_t,
    const __bf16* __restrict__ kb_s, const __bf16* __restrict__ kb_t,
    const __bf16* __restrict__ vt_s, const __bf16* __restrict__ vt_t,
    const __bf16* __restrict__ emaskb,
    __bf16* __restrict__ att_s, __bf16* __restrict__ att_t)
{
    const int b    = blockIdx.z;
    const int wave = threadIdx.x >> 6;
    const int combo = blockIdx.y * 4 + wave;
    const int br = combo & 1;
    const int h  = combo >> 1;
    const __bf16* Q  = br ? qb_t : qb_s;
    const __bf16* K  = br ? kb_t : kb_s;
    const __bf16* Vt = br ? vt_t : vt_s;
    __bf16* O        = br ? att_t : att_s;
    const int lane = threadIdx.x & 63;
    const int quad = lane >> 4, lq = lane & 15;
    const int col  = lane & 31;         // 32x32 column (key)
    const int half = lane >> 5;         // 32x32 row-half
    const int bh = b * HH + h;
    const int p0 = blockIdx.x * 32;

    __shared__ __align__(16) __bf16 S[4][32][36];   // per-wave 32x32 scores (+pad)

    int pq = p0 + col; if (pq > 999) pq = 999;
    short8_t qA = *(const short8_t*)&Q[(((size_t)bh * 1000 + pq) << 4) + half * 8];

    short8_t onesB = { (short)0x3F80, (short)0x3F80, (short)0x3F80, (short)0x3F80,
                       (short)0x3F80, (short)0x3F80, (short)0x3F80, (short)0x3F80 };

    f32x4 o[2] = { {0.f,0.f,0.f,0.f}, {0.f,0.f,0.f,0.f} };
    f32x4 l[2] = { {0.f,0.f,0.f,0.f}, {0.f,0.f,0.f,0.f} };

    // 8 emask row-pair pointers (pair j covers C rows {2j,2j+1}); second row
    // via +1000-element (2000B) immediate offset.
    const __bf16* mrow[8];
    #pragma unroll
    for (int j = 0; j < 8; ++j) {
        int row = p0 + ((2 * j) & 3) + 8 * (j >> 1) + 4 * half;
        if (row > 998) row = 998;       // keep row+1 in-bounds; garbage discarded
        mrow[j] = emaskb + ((size_t)b * 1000 + row) * 1000 + col;
    }

    // prologue: K/V frags for keys 0..31
    short8_t kBc = *(const short8_t*)&K[(((size_t)bh * 1000 + col) << 4) + half * 8];
    short8_t vBc = *(const short8_t*)&Vt[(((size_t)bh * 16 + lq) << 10) + quad * 8];

    for (int n0 = 0; n0 < 992; n0 += 32) {
        int nk = n0 + 32 + col; if (nk > 999) nk = 999;
        short8_t kBn = *(const short8_t*)&K[(((size_t)bh * 1000 + nk) << 4) + half * 8];
        short8_t vBn = *(const short8_t*)&Vt[(((size_t)bh * 16 + lq) << 10) + n0 + 32 + quad * 8];

        float mk[16];
        #pragma unroll
        for (int j = 0; j < 8; ++j) {
            mk[2 * j]     = (float)mrow[j][0];
            mk[2 * j + 1] = (float)mrow[j][1000];
            mrow[j] += 32;
        }

        f32x16 s = mfma32(qA, kBc, f32x16{});

        __threadfence_block();
        #pragma unroll
        for (int reg = 0; reg < 16; ++reg) {
            float e = __expf(s[reg]) * mk[reg];
            S[wave][(reg & 3) + 8 * (reg >> 2) + 4 * half][col] = (__bf16)e;
        }
        __threadfence_block();

        #pragma unroll
        for (int t = 0; t < 2; ++t) {
            uint2 L = *(const uint2*)&S[wave][t * 16 + lq][quad * 4];
            uint2 H = *(const uint2*)&S[wave][t * 16 + lq][16 + quad * 4];
            unsigned u0 = __builtin_amdgcn_perm(H.x, L.x, 0x05040100u);
            unsigned u1 = __builtin_amdgcn_perm(H.x, L.x, 0x07060302u);
            unsigned u2 = __builtin_amdgcn_perm(H.y, L.y, 0x05040100u);
            unsigned u3 = __builtin_amdgcn_perm(H.y, L.y, 0x07060302u);
            uint4 u4 = make_uint4(u0, u1, u2, u3);
            short8_t aP = __builtin_bit_cast(short8_t, u4);
            o[t] = mfma16(aP, vBc, o[t]);
            l[t] = mfma16(aP, onesB, l[t]);
        }
        kBc = kBn; vBc = vBn;
    }

    // tail: keys 992..999 (valid iff col < 8); kBc clamped, vBc zero-pad
    {
        f32x16 s = mfma32(qA, kBc, f32x16{});
        __threadfence_block();
        #pragma unroll
        for (int reg = 0; reg < 16; ++reg) {
            int j = reg >> 1;
            float mkv = (col < 8) ? (float)((reg & 1) ? mrow[j][1000] : mrow[j][0]) : 0.f;
            float e = __expf(s[reg]) * mkv;           // mkv=0 kills invalid keys
            S[wave][(reg & 3) + 8 * (reg >> 2) + 4 * half][col] = (__bf16)e;
        }
        __threadfence_block();
        #pragma unroll
        for (int t = 0; t < 2; ++t) {
            uint2 L = *(const uint2*)&S[wave][t * 16 + lq][quad * 4];
            uint2 H = *(const uint2*)&S[wave][t * 16 + lq][16 + quad * 4];
            unsigned u0 = __builtin_amdgcn_perm(H.x, L.x, 0x05040100u);
            unsigned u1 = __builtin_amdgcn_perm(H.x, L.x, 0x07060302u);
            unsigned u2 = __builtin_amdgcn_perm(H.y, L.y, 0x05040100u);
            unsigned u3 = __builtin_amdgcn_perm(H.y, L.y, 0x07060302u);
            uint4 u4 = make_uint4(u0, u1, u2, u3);
            short8_t aP = __builtin_bit_cast(short8_t, u4);
            o[t] = mfma16(aP, vBc, o[t]);
            l[t] = mfma16(aP, onesB, l[t]);
        }
    }

    #pragma unroll
    for (int t = 0; t < 2; ++t)
        #pragma unroll
        for (int r = 0; r < 4; ++r) {
            int p = p0 + t * 16 + quad * 4 + r;
            if (p < 1000)
                O[((size_t)b * 1000 + p) * 128 + h * 16 + lq] = (__bf16)(o[t][r] / l[t][r]);
        }
}

// ---------------------------------------------------------------------------
// K3: MFMA combine WITH INLINE GATE:
// gated = g*(att_s@Wc_s+bc_s) + (1-g)*(att_t@Wc_t+bc_t), g = sigmoid(inb@Wg+bg)
// 128 threads (2 waves x 16 rows), grid 250.
// ---------------------------------------------------------------------------
__global__ __launch_bounds__(128) void combine_mfma_kernel(
    const __bf16* __restrict__ att_s, const __bf16* __restrict__ att_t,
    const __bf16* __restrict__ inb, const __bf16* __restrict__ Wtb,
    const float* __restrict__ bc_s, const float* __restrict__ bc_t,
    const float* __restrict__ bg, __bf16* __restrict__ gatedb)
{
    const int wave = threadIdx.x >> 6, lane = threadIdx.x & 63;
    const int quad = lane >> 4, lq = lane & 15;
    const int r0 = blockIdx.x * 32 + wave * 16;
    const __bf16* Wgp = Wtb + 106496;
    const __bf16* Ws  = Wtb + 126976;
    const __bf16* Wt  = Wtb + 143360;

    short8_t aS[4], aT[4], aG[5];
    #pragma unroll
    for (int c = 0; c < 4; ++c) {
        aS[c] = *(const short8_t*)&att_s[(size_t)(r0 + lq) * 128 + c * 32 + quad * 8];
        aT[c] = *(const short8_t*)&att_t[(size_t)(r0 + lq) * 128 + c * 32 + quad * 8];
    }
    #pragma unroll
    for (int c = 0; c < 5; ++c)
        aG[c] = *(const short8_t*)&inb[(size_t)(r0 + lq) * 160 + c * 32 + quad * 8];

    #pragma unroll
    for (int nt = 0; nt < 8; ++nt) {
        f32x4 accS = {0.f,0.f,0.f,0.f}, accT = accS, accG = accS;
        #pragma unroll
        for (int c = 0; c < 4; ++c) {
            short8_t bS = *(const short8_t*)&Ws[(size_t)(nt * 16 + lq) * 128 + c * 32 + quad * 8];
            short8_t bT = *(const short8_t*)&Wt[(size_t)(nt * 16 + lq) * 128 + c * 32 + quad * 8];
            accS = mfma16(aS[c], bS, accS);
            accT = mfma16(aT[c], bT, accT);
        }
        #pragma unroll
        for (int c = 0; c < 5; ++c) {
            short8_t bG = *(const short8_t*)&Wgp[(size_t)(nt * 16 + lq) * 160 + c * 32 + quad * 8];
            accG = mfma16(aG[c], bG, accG);
        }
        int f = nt * 16 + lq;
        float b1 = bc_s[f], b2 = bc_t[f], b3 = bg[f];
        #pragma unroll
        for (int r = 0; r < 4; ++r) {
            int m = r0 + quad * 4 + r;
            float g = sigmoid_fast(accG[r] + b3);
            float val = g * (accS[r] + b1) + (1.f - g) * (accT[r] + b2);
            gatedb[(size_t)m * 128 + f] = (__bf16)val;
        }
    }
}

// ---------------------------------------------------------------------------
// K4: FUSED pointer scores + clip + emask + row softmax -> probs in d_out.
// ---------------------------------------------------------------------------
__global__ __launch_bounds__(256) void pointer_softmax_kernel(
    const __bf16* __restrict__ gb, const __bf16* __restrict__ nb,
    const __bf16* __restrict__ emaskb, float* __restrict__ out)
{
    const int b    = blockIdx.y;
    const int p0   = blockIdx.x * 16;
    const int wave = threadIdx.x >> 6;
    const int lane = threadIdx.x & 63;
    const int quad = lane >> 4, lq = lane & 15;

    __shared__ float Spart[4][16];

    short8_t aF[4];
    {
        int pp = p0 + lq; if (pp > 999) pp = 999;
        const __bf16* arow = gb + (((size_t)b * 1000 + pp) << 7) + quad * 8;
        #pragma unroll
        for (int kc = 0; kc < 4; ++kc) aF[kc] = *(const short8_t*)&arow[kc * 32];
    }

    float ev[16][4];
    float psum[4] = {0.f, 0.f, 0.f, 0.f};

    #pragma unroll
    for (int i = 0; i < 16; ++i) {
        const int nt = i * 4 + wave;          // 0..63
        const int nn = nt * 16 + lq;
        const bool nv = nn < 1000;
        int nc = nv ? nn : 999;
        const __bf16* brow = nb + (((size_t)b * 1000 + nc) << 7) + quad * 8;
        f32x4 acc = {0.f, 0.f, 0.f, 0.f};
        #pragma unroll
        for (int kc = 0; kc < 4; ++kc) {
            short8_t bF = *(const short8_t*)&brow[kc * 32];
            acc = mfma16(aF[kc], bF, acc);
        }
        #pragma unroll
        for (int r = 0; r < 4; ++r) {
            int p = p0 + quad * 4 + r;
            bool v = nv && (p < 1000);
            size_t midx = v ? ((size_t)b * 1000 + p) * 1000 + nn : 0;
            float mk = (float)emaskb[midx];
            float sc = 10.f * tanh_fast(acc[r] * INV_SQRT_E);
            float ee = v ? __expf(sc) * mk : 0.f;
            ev[i][r] = ee;
            psum[r] += ee;
        }
    }

    #pragma unroll
    for (int r = 0; r < 4; ++r) psum[r] = sum16(psum[r]);
    if (lq == 0) {
        #pragma unroll
        for (int r = 0; r < 4; ++r) Spart[wave][quad * 4 + r] = psum[r];
    }
    __syncthreads();
    float inv[4];
    #pragma unroll
    for (int r = 0; r < 4; ++r) {
        int row = quad * 4 + r;
        float s = Spart[0][row] + Spart[1][row] + Spart[2][row] + Spart[3][row];
        inv[r] = 1.f / s;
    }

    #pragma unroll
    for (int i = 0; i < 16; ++i) {
        const int nt = i * 4 + wave;
        const int nn = nt * 16 + lq;
        if (nn < 1000) {
            #pragma unroll
            for (int r = 0; r < 4; ++r) {
                int p = p0 + quad * 4 + r;
                if (p < 1000)
                    out[((size_t)b * 1000 + p) * 1000 + nn] = ev[i][r] * inv[r];
            }
        }
    }
}

// ---------------------------------------------------------------------------
extern "C" void kernel_launch(void* const* d_in, const int* in_sizes, int n_in,
                              void* d_out, int out_size, void* d_ws, size_t ws_size,
                              hipStream_t stream)
{
    const float* eln   = (const float*)d_in[0];
    const float* attr  = (const float*)d_in[1];
    const float* nodes = (const float*)d_in[2];
    const float* mask  = (const float*)d_in[3];
    const float* Wq_s  = (const float*)d_in[4];
    const float* Wk_s  = (const float*)d_in[5];
    const float* Wv_s  = (const float*)d_in[6];
    const float* Wq_t  = (const float*)d_in[7];
    const float* Wk_t  = (const float*)d_in[8];
    const float* Wv_t  = (const float*)d_in[9];
    const float* Wc_s  = (const float*)d_in[10];
    const float* bc_s  = (const float*)d_in[11];
    const float* Wc_t  = (const float*)d_in[12];
    const float* bc_t  = (const float*)d_in[13];
    const float* Wg    = (const float*)d_in[14];
    const float* bg    = (const float*)d_in[15];
    float* out = (float*)d_out;

    char* w = (char*)d_ws;
    const size_t KB_SZ = (size_t)64 * 1000 * 16 * 2;   // 2,048,000 B
    const size_t VT_SZ = (size_t)64 * 16 * 1024 * 2;   // 2,097,152 B
    const size_t H_SZ  = (size_t)8000 * 128 * 2;       // 2,048,000 B
    const size_t IN_SZ = (size_t)8000 * 160 * 2;       // 2,560,000 B
    const size_t EM_SZ = (size_t)8000 * 1000 * 2;      // 16,000,000 B
    __bf16* kb_s  = (__bf16*)w;           w += KB_SZ;
    __bf16* kb_t  = (__bf16*)w;           w += KB_SZ;
    __bf16* qb_s  = (__bf16*)w;           w += KB_SZ;
    __bf16* qb_t  = (__bf16*)w;           w += KB_SZ;
    __bf16* vt_s  = (__bf16*)w;           w += VT_SZ;
    __bf16* vt_t  = (__bf16*)w;           w += VT_SZ;
    __bf16* att_s = (__bf16*)w;           w += H_SZ;
    __bf16* att_t = (__bf16*)w;           w += H_SZ;
    __bf16* gatedb = (__bf16*)w;          w += H_SZ;
    __bf16* nodesb = (__bf16*)w;          w += H_SZ;
    __bf16* inb    = (__bf16*)w;          w += IN_SZ;
    __bf16* emaskb = (__bf16*)w;          w += EM_SZ;
    __bf16* Wtb    = (__bf16*)w;          w += 320000;
    // total ~39.5 MB (< 41 MB proven in round 1)

    // zero V-transposed pads so tail B-frags are exact zeros
    hipMemsetAsync(vt_s, 0, 2 * VT_SZ, stream);

    prep_kernel<<<dim3(9483), 256, 0, stream>>>(
        mask, nodes, eln, attr, Wk_s, Wv_s, Wk_t, Wv_t, Wq_s, Wq_t, Wg,
        Wc_s, Wc_t, emaskb, nodesb, inb, Wtb);
    proj_mfma_kernel<<<dim3(125, 6), 256, 0, stream>>>(
        nodesb, inb, Wtb, kb_s, vt_s, kb_t, vt_t, qb_s, qb_t);
    attn_mfma_kernel<<<dim3(32, 4, 8), 256, 0, stream>>>(
        qb_s, qb_t, kb_s, kb_t, vt_s, vt_t, emaskb, att_s, att_t);
    combine_mfma_kernel<<<dim3(250), 128, 0, stream>>>(
        att_s, att_t, inb, Wtb, bc_s, bc_t, bg, gatedb);
    pointer_softmax_kernel<<<dim3(63, 8), 256, 0, stream>>>(
        gatedb, nodesb, emaskb, out);
}